// Round 4
// baseline (686.117 us; speedup 1.0000x reference)
//
#include <hip/hip_runtime.h>
#include <math.h>

#define NN 20000      // nodes
#define NE 320000     // edges (without self loops)
#define NT 340000     // edges + self loops
#define NG 64         // graphs

__device__ __forceinline__ float lrelu(float v) { return v > 0.f ? v : 0.2f * v; }
__device__ __forceinline__ float elu1(float v)  { return v > 0.f ? v : (expf(v) - 1.f); }
__device__ __forceinline__ float bflo(unsigned u) { return __uint_as_float(u << 16); }
__device__ __forceinline__ float bfhi(unsigned u) { return __uint_as_float(u & 0xFFFF0000u); }
__device__ __forceinline__ unsigned short f2bf(float f) {
    unsigned u = __float_as_uint(f);
    u += 0x7FFFu + ((u >> 16) & 1u);   // round to nearest even
    return (unsigned short)(u >> 16);
}

__device__ __forceinline__ int esrc(const int* ei, int e) { return e < NE ? ei[e] : (e - NE); }
__device__ __forceinline__ int edst(const int* ei, int e) { return e < NE ? ei[NE + e] : (e - NE); }

// ---------- CSR build (by dst) + graph node counts ----------
__global__ void k_hist(const int* __restrict__ ei, const int* __restrict__ batch,
                       int* __restrict__ deg, float* __restrict__ cnt) {
    int t = blockIdx.x * blockDim.x + threadIdx.x;
    if (t < NN) atomicAdd(&cnt[batch[t]], 1.0f);
    if (t >= NT) return;
    atomicAdd(&deg[edst(ei, t)], 1);
}

// single-block exclusive scan of deg[20000] -> rowstart[20001], cursor copy
__global__ void k_scan(const int* __restrict__ deg, int* __restrict__ rowstart,
                       int* __restrict__ cursor) {
    __shared__ int part[1024];
    int t = threadIdx.x;
    int base = t * 20;
    int local[20];
    int s = 0;
    if (base < NN) {
#pragma unroll
        for (int i = 0; i < 20; ++i) { local[i] = deg[base + i]; s += local[i]; }
    }
    part[t] = s;
    __syncthreads();
    for (int o = 1; o < 1024; o <<= 1) {
        int v = (t >= o) ? part[t - o] : 0;
        __syncthreads();
        part[t] += v;
        __syncthreads();
    }
    if (base < NN) {
        int run = (t == 0) ? 0 : part[t - 1];
#pragma unroll
        for (int i = 0; i < 20; ++i) {
            rowstart[base + i] = run;
            cursor[base + i] = run;
            run += local[i];
        }
    }
    if (t == 1023) rowstart[NN] = part[1023];
}

__global__ void k_scatter(const int* __restrict__ ei, int* __restrict__ cursor,
                          int* __restrict__ csr_src) {
    int t = blockIdx.x * blockDim.x + threadIdx.x;
    if (t >= NT) return;
    int d = edst(ei, t), s = esrc(ei, t);
    int pos = atomicAdd(&cursor[d], 1);
    csr_src[pos] = s;
}

// ---------- layer 1 ----------
// h1bf[n][64] = bf16(x[n][3] @ W1[3][64]); al_s1/al_d1[n][8] head-wise dots (f32)
__global__ void k1_h1(const float* __restrict__ x, const float* __restrict__ W1,
                      const float* __restrict__ as1, const float* __restrict__ ad1,
                      unsigned short* __restrict__ h1bf, float* __restrict__ al_s,
                      float* __restrict__ al_d) {
    int n = blockIdx.x * 4 + (threadIdx.x >> 6);
    int j = threadIdx.x & 63;
    float x0 = x[n * 3 + 0], x1 = x[n * 3 + 1], x2 = x[n * 3 + 2];
    float v = fmaf(x0, W1[j], fmaf(x1, W1[64 + j], x2 * W1[128 + j]));
    h1bf[n * 64 + j] = f2bf(v);
    float ps = v * as1[j];
    float pd = v * ad1[j];
    for (int o = 4; o >= 1; o >>= 1) {
        ps += __shfl_xor(ps, o, 8);
        pd += __shfl_xor(pd, o, 8);
    }
    if ((j & 7) == 0) {
        al_s[n * 8 + (j >> 3)] = ps;
        al_d[n * 8 + (j >> 3)] = pd;
    }
}

// fused layer-1 softmax + aggregate + bias + elu. 1 wave per node, lane = channel.
__global__ void k_l1(const int* __restrict__ rowstart, const int* __restrict__ csr_src,
                     const float* __restrict__ al_s, const float* __restrict__ al_d,
                     const unsigned short* __restrict__ h1bf, const float* __restrict__ b1,
                     float* __restrict__ o1) {
    int n = blockIdx.x * 4 + (threadIdx.x >> 6);
    int j = threadIdx.x & 63;  // channel
    int h = j >> 3;            // head
    float ald = al_d[n * 8 + h];
    int start = rowstart[n], end = rowstart[n + 1];
    // pass 1: per-head max, edges strided over the 8 lanes of the head group
    float m = -1e30f;
    for (int e = start + (j & 7); e < end; e += 8) {
        m = fmaxf(m, lrelu(al_s[csr_src[e] * 8 + h] + ald));
    }
    for (int o = 4; o >= 1; o >>= 1) m = fmaxf(m, __shfl_xor(m, o, 8));
    // pass 2: weighted aggregate
    float denom = 0.f, acc = 0.f;
    for (int e = start; e < end; ++e) {
        int s = csr_src[e];
        float ex = __expf(lrelu(al_s[s * 8 + h] + ald) - m);
        denom += ex;
        float hv = __uint_as_float(((unsigned)h1bf[s * 64 + j]) << 16);
        acc = fmaf(ex, hv, acc);
    }
    o1[n * 64 + j] = elu1(acc / denom + b1[j]);
}

// h2bf = bf16(o1 @ W2), tiled 16 nodes/block so W2 stays in L2
__global__ void k5b_h2(const float* __restrict__ o1, const float* __restrict__ W2,
                       unsigned short* __restrict__ h2bf) {
    __shared__ float sO[16][64];
    int n0 = blockIdx.x * 16;
    int j = threadIdx.x;  // 512
    for (int i = j; i < 1024; i += 512) sO[i >> 6][i & 63] = o1[n0 * 64 + i];
    __syncthreads();
    float acc[16];
#pragma unroll
    for (int i = 0; i < 16; ++i) acc[i] = 0.f;
    for (int k = 0; k < 64; ++k) {
        float wv = W2[k * 512 + j];
#pragma unroll
        for (int i = 0; i < 16; ++i) acc[i] = fmaf(sO[i][k], wv, acc[i]);
    }
#pragma unroll
    for (int i = 0; i < 16; ++i) h2bf[(n0 + i) * 512 + j] = f2bf(acc[i]);
}

// al_s2/al_d2[n] = dot(h2[n], a2).  one wave per node.
__global__ void k5c_logits(const unsigned short* __restrict__ h2bf,
                           const float* __restrict__ as2, const float* __restrict__ ad2,
                           float* __restrict__ al_s2, float* __restrict__ al_d2) {
    int w = threadIdx.x >> 6, lane = threadIdx.x & 63;
    int n = blockIdx.x * 4 + w;
    uint4 hv = *(const uint4*)(h2bf + n * 512 + lane * 8);
    const float4* sp = (const float4*)(as2 + lane * 8);
    const float4* dp = (const float4*)(ad2 + lane * 8);
    float4 s0 = sp[0], s1 = sp[1];
    float4 d0 = dp[0], d1 = dp[1];
    float f0 = bflo(hv.x), f1 = bfhi(hv.x), f2 = bflo(hv.y), f3 = bfhi(hv.y);
    float f4 = bflo(hv.z), f5 = bfhi(hv.z), f6 = bflo(hv.w), f7 = bfhi(hv.w);
    float ps = f0 * s0.x + f1 * s0.y + f2 * s0.z + f3 * s0.w
             + f4 * s1.x + f5 * s1.y + f6 * s1.z + f7 * s1.w;
    float pd = f0 * d0.x + f1 * d0.y + f2 * d0.z + f3 * d0.w
             + f4 * d1.x + f5 * d1.y + f6 * d1.z + f7 * d1.w;
    for (int o = 32; o >= 1; o >>= 1) {
        ps += __shfl_xor(ps, o, 64);
        pd += __shfl_xor(pd, o, 64);
    }
    if (lane == 0) { al_s2[n] = ps; al_d2[n] = pd; }
}

// fused layer-2 softmax + aggregate + bias + elu + mean-pool scatter.
// 1 wave per node; lane owns 8 channels (one uint4 = 16B per edge).
__global__ void k_l2(const int* __restrict__ rowstart, const int* __restrict__ csr_src,
                     const float* __restrict__ al_s2, const float* __restrict__ al_d2,
                     const unsigned short* __restrict__ h2bf, const float* __restrict__ b2,
                     const int* __restrict__ batch, float* __restrict__ sums) {
    int n = blockIdx.x * 4 + (threadIdx.x >> 6);
    int lane = threadIdx.x & 63;
    float ald = al_d2[n];
    int start = rowstart[n], end = rowstart[n + 1];
    // pass 1: max, lane-parallel over edges
    float m = -1e30f;
    for (int e = start + lane; e < end; e += 64) {
        m = fmaxf(m, lrelu(al_s2[csr_src[e]] + ald));
    }
    for (int o = 32; o >= 1; o >>= 1) m = fmaxf(m, __shfl_xor(m, o, 64));
    // pass 2: weighted aggregate (wave-uniform ex; per-lane 8-channel fragment)
    float denom = 0.f;
    float acc[8] = {0.f, 0.f, 0.f, 0.f, 0.f, 0.f, 0.f, 0.f};
    for (int e = start; e < end; ++e) {
        int s = csr_src[e];
        float ex = __expf(lrelu(al_s2[s] + ald) - m);
        denom += ex;
        uint4 hv = *(const uint4*)(h2bf + s * 512 + lane * 8);
        acc[0] = fmaf(ex, bflo(hv.x), acc[0]);
        acc[1] = fmaf(ex, bfhi(hv.x), acc[1]);
        acc[2] = fmaf(ex, bflo(hv.y), acc[2]);
        acc[3] = fmaf(ex, bfhi(hv.y), acc[3]);
        acc[4] = fmaf(ex, bflo(hv.z), acc[4]);
        acc[5] = fmaf(ex, bfhi(hv.z), acc[5]);
        acc[6] = fmaf(ex, bflo(hv.w), acc[6]);
        acc[7] = fmaf(ex, bfhi(hv.w), acc[7]);
    }
    float inv = 1.f / denom;
    int g = batch[n];
    float* sp = sums + g * 512 + lane * 8;
    const float* bp = b2 + lane * 8;
#pragma unroll
    for (int k = 0; k < 8; ++k) {
        atomicAdd(&sp[k], elu1(acc[k] * inv + bp[k]));
    }
}

// out[g][j] = (sums[g]/max(cnt,1)) @ Wo + bo
__global__ void k10_final(const float* __restrict__ sums, const float* __restrict__ cnt,
                          const float* __restrict__ Wo, const float* __restrict__ bo,
                          float* __restrict__ out) {
    __shared__ float sp[512];
    int g = blockIdx.x, j = threadIdx.x;
    float c = cnt[g];
    c = c > 0.f ? c : 1.f;
    sp[j] = sums[g * 512 + j] / c;
    __syncthreads();
    float v = bo[j];
    for (int k = 0; k < 512; ++k) v = fmaf(sp[k], Wo[k * 512 + j], v);
    out[g * 512 + j] = v;
}

extern "C" void kernel_launch(void* const* d_in, const int* in_sizes, int n_in,
                              void* d_out, int out_size, void* d_ws, size_t ws_size,
                              hipStream_t stream) {
    const float* x     = (const float*)d_in[0];
    const int*   ei    = (const int*)d_in[1];    // [2, NE]
    const int*   batch = (const int*)d_in[2];    // [NN]
    const float* W1    = (const float*)d_in[3];
    const float* as1   = (const float*)d_in[4];
    const float* ad1   = (const float*)d_in[5];
    const float* b1    = (const float*)d_in[6];
    const float* W2    = (const float*)d_in[7];
    const float* as2   = (const float*)d_in[8];
    const float* ad2   = (const float*)d_in[9];
    const float* b2    = (const float*)d_in[10];
    const float* Wo    = (const float*)d_in[11];
    const float* bo    = (const float*)d_in[12];
    float* out = (float*)d_out;

    // ---- workspace arena (float/4-byte units) ----
    // NOTE: h1bf = NN*64 ushorts = 2,560,000 bytes = 640,000 float units (R2 bug: was 320,000)
    float* w = (float*)d_ws;
    unsigned short* h1bf = (unsigned short*)(w + 0);        // 640,000 units
    float* al_s1 = w + 640000;    // 160,000
    float* al_d1 = w + 800000;    // 160,000
    float* o1    = w + 960000;    // 1,280,000
    unsigned short* h2bf = (unsigned short*)(w + 2240000);  // NN*512 ushorts = 5,120,000 units (byte 8,960,000: 16B aligned)
    float* al_s2 = w + 7360000;   // 20,000
    float* al_d2 = w + 7380000;   // 20,000
    int*   rowstart = (int*)(w + 7400000);   // 20,001
    int*   cursor   = (int*)(w + 7420004);   // 20,000
    int*   csr_src  = (int*)(w + 7440004);   // 340,000
    // ---- zero-initialized region ----
    int*   deg  = (int*)(w + 7780004);       // 20,000
    float* sums = w + 7800004;               // 32,768
    float* cnt  = w + 7832772;               // 64
    // end: 7,832,836 units ≈ 31.3 MB

    hipMemsetAsync(w + 7780004, 0, (size_t)(7832836 - 7780004) * 4, stream);

    k_hist   <<<(NT + 255) / 256, 256, 0, stream>>>(ei, batch, deg, cnt);
    k_scan   <<<1, 1024, 0, stream>>>(deg, rowstart, cursor);
    k_scatter<<<(NT + 255) / 256, 256, 0, stream>>>(ei, cursor, csr_src);

    k1_h1    <<<NN / 4, 256, 0, stream>>>(x, W1, as1, ad1, h1bf, al_s1, al_d1);
    k_l1     <<<NN / 4, 256, 0, stream>>>(rowstart, csr_src, al_s1, al_d1, h1bf, b1, o1);
    k5b_h2   <<<NN / 16, 512, 0, stream>>>(o1, W2, h2bf);
    k5c_logits<<<NN / 4, 256, 0, stream>>>(h2bf, as2, ad2, al_s2, al_d2);
    k_l2     <<<NN / 4, 256, 0, stream>>>(rowstart, csr_src, al_s2, al_d2, h2bf, b2, batch, sums);

    k10_final<<<NG, 512, 0, stream>>>(sums, cnt, Wo, bo, out);
}

// Round 5
// 355.743 us; speedup vs baseline: 1.9287x; 1.9287x over previous
//
#include <hip/hip_runtime.h>
#include <math.h>

#define NN 20000      // nodes
#define NE 320000     // edges (without self loops)
#define NT 340000     // edges + self loops
#define NG 64         // graphs

__device__ __forceinline__ float lrelu(float v) { return v > 0.f ? v : 0.2f * v; }
__device__ __forceinline__ float elu1(float v)  { return v > 0.f ? v : (expf(v) - 1.f); }
__device__ __forceinline__ float bflo(unsigned u) { return __uint_as_float(u << 16); }
__device__ __forceinline__ float bfhi(unsigned u) { return __uint_as_float(u & 0xFFFF0000u); }
__device__ __forceinline__ unsigned short f2bf(float f) {
    unsigned u = __float_as_uint(f);
    u += 0x7FFFu + ((u >> 16) & 1u);   // round to nearest even
    return (unsigned short)(u >> 16);
}

__device__ __forceinline__ int esrc(const int* ei, int e) { return e < NE ? ei[e] : (e - NE); }
__device__ __forceinline__ int edst(const int* ei, int e) { return e < NE ? ei[NE + e] : (e - NE); }

// ---------- CSR build (by dst) ----------
__global__ void k_hist(const int* __restrict__ ei, int* __restrict__ deg) {
    int t = blockIdx.x * blockDim.x + threadIdx.x;
    if (t >= NT) return;
    atomicAdd(&deg[edst(ei, t)], 1);
}

// single-block: exclusive scan of deg -> rowstart/cursor; binary-search gstart from sorted batch
__global__ void k_scan(const int* __restrict__ deg, const int* __restrict__ batch,
                       int* __restrict__ rowstart, int* __restrict__ cursor,
                       int* __restrict__ gstart) {
    __shared__ int part[1024];
    int t = threadIdx.x;
    int base = t * 20;
    int local[20];
    int s = 0;
    if (base < NN) {
#pragma unroll
        for (int i = 0; i < 20; ++i) { local[i] = deg[base + i]; s += local[i]; }
    }
    part[t] = s;
    __syncthreads();
    for (int o = 1; o < 1024; o <<= 1) {
        int v = (t >= o) ? part[t - o] : 0;
        __syncthreads();
        part[t] += v;
        __syncthreads();
    }
    if (base < NN) {
        int run = (t == 0) ? 0 : part[t - 1];
#pragma unroll
        for (int i = 0; i < 20; ++i) {
            rowstart[base + i] = run;
            cursor[base + i] = run;
            run += local[i];
        }
    }
    if (t == 1023) rowstart[NN] = part[1023];
    if (t <= NG) {  // gstart[t] = first node with batch >= t (batch sorted)
        int lo = 0, hi = NN;
        while (lo < hi) {
            int mid = (lo + hi) >> 1;
            if (batch[mid] < t) lo = mid + 1; else hi = mid;
        }
        gstart[t] = lo;
    }
}

__global__ void k_scatter(const int* __restrict__ ei, int* __restrict__ cursor,
                          int* __restrict__ csr_src) {
    int t = blockIdx.x * blockDim.x + threadIdx.x;
    if (t >= NT) return;
    int d = edst(ei, t), s = esrc(ei, t);
    int pos = atomicAdd(&cursor[d], 1);
    csr_src[pos] = s;
}

// ---------- layer 1 ----------
__global__ void k1_h1(const float* __restrict__ x, const float* __restrict__ W1,
                      const float* __restrict__ as1, const float* __restrict__ ad1,
                      unsigned short* __restrict__ h1bf, float* __restrict__ al_s,
                      float* __restrict__ al_d) {
    int n = blockIdx.x * 4 + (threadIdx.x >> 6);
    int j = threadIdx.x & 63;
    float x0 = x[n * 3 + 0], x1 = x[n * 3 + 1], x2 = x[n * 3 + 2];
    float v = fmaf(x0, W1[j], fmaf(x1, W1[64 + j], x2 * W1[128 + j]));
    h1bf[n * 64 + j] = f2bf(v);
    float ps = v * as1[j];
    float pd = v * ad1[j];
    for (int o = 4; o >= 1; o >>= 1) {
        ps += __shfl_xor(ps, o, 8);
        pd += __shfl_xor(pd, o, 8);
    }
    if ((j & 7) == 0) {
        al_s[n * 8 + (j >> 3)] = ps;
        al_d[n * 8 + (j >> 3)] = pd;
    }
}

// fused layer-1 softmax + aggregate + bias + elu. 1 wave per node, lane = channel.
__global__ void k_l1(const int* __restrict__ rowstart, const int* __restrict__ csr_src,
                     const float* __restrict__ al_s, const float* __restrict__ al_d,
                     const unsigned short* __restrict__ h1bf, const float* __restrict__ b1,
                     float* __restrict__ o1) {
    int n = blockIdx.x * 4 + (threadIdx.x >> 6);
    int j = threadIdx.x & 63;  // channel
    int h = j >> 3;            // head
    float ald = al_d[n * 8 + h];
    int start = rowstart[n], end = rowstart[n + 1];
    float m = -1e30f;
    for (int e = start + (j & 7); e < end; e += 8) {
        m = fmaxf(m, lrelu(al_s[csr_src[e] * 8 + h] + ald));
    }
    for (int o = 4; o >= 1; o >>= 1) m = fmaxf(m, __shfl_xor(m, o, 8));
    float denom = 0.f, acc = 0.f;
    for (int e = start; e < end; ++e) {
        int s = csr_src[e];
        float ex = __expf(lrelu(al_s[s * 8 + h] + ald) - m);
        denom += ex;
        float hv = __uint_as_float(((unsigned)h1bf[s * 64 + j]) << 16);
        acc = fmaf(ex, hv, acc);
    }
    o1[n * 64 + j] = elu1(acc / denom + b1[j]);
}

// h2bf = bf16(o1 @ W2), tiled 16 nodes/block so W2 stays in L2
__global__ void k5b_h2(const float* __restrict__ o1, const float* __restrict__ W2,
                       unsigned short* __restrict__ h2bf) {
    __shared__ float sO[16][64];
    int n0 = blockIdx.x * 16;
    int j = threadIdx.x;  // 512
    for (int i = j; i < 1024; i += 512) sO[i >> 6][i & 63] = o1[n0 * 64 + i];
    __syncthreads();
    float acc[16];
#pragma unroll
    for (int i = 0; i < 16; ++i) acc[i] = 0.f;
    for (int k = 0; k < 64; ++k) {
        float wv = W2[k * 512 + j];
#pragma unroll
        for (int i = 0; i < 16; ++i) acc[i] = fmaf(sO[i][k], wv, acc[i]);
    }
#pragma unroll
    for (int i = 0; i < 16; ++i) h2bf[(n0 + i) * 512 + j] = f2bf(acc[i]);
}

// al_s2/al_d2[n] = dot(h2[n], a2).  one wave per node.
__global__ void k5c_logits(const unsigned short* __restrict__ h2bf,
                           const float* __restrict__ as2, const float* __restrict__ ad2,
                           float* __restrict__ al_s2, float* __restrict__ al_d2) {
    int w = threadIdx.x >> 6, lane = threadIdx.x & 63;
    int n = blockIdx.x * 4 + w;
    uint4 hv = *(const uint4*)(h2bf + n * 512 + lane * 8);
    const float4* sp = (const float4*)(as2 + lane * 8);
    const float4* dp = (const float4*)(ad2 + lane * 8);
    float4 s0 = sp[0], s1 = sp[1];
    float4 d0 = dp[0], d1 = dp[1];
    float f0 = bflo(hv.x), f1 = bfhi(hv.x), f2 = bflo(hv.y), f3 = bfhi(hv.y);
    float f4 = bflo(hv.z), f5 = bfhi(hv.z), f6 = bflo(hv.w), f7 = bfhi(hv.w);
    float ps = f0 * s0.x + f1 * s0.y + f2 * s0.z + f3 * s0.w
             + f4 * s1.x + f5 * s1.y + f6 * s1.z + f7 * s1.w;
    float pd = f0 * d0.x + f1 * d0.y + f2 * d0.z + f3 * d0.w
             + f4 * d1.x + f5 * d1.y + f6 * d1.z + f7 * d1.w;
    for (int o = 32; o >= 1; o >>= 1) {
        ps += __shfl_xor(ps, o, 64);
        pd += __shfl_xor(pd, o, 64);
    }
    if (lane == 0) { al_s2[n] = ps; al_d2[n] = pd; }
}

// fused layer-2 softmax + aggregate + bias + elu -> o2 (plain coalesced stores, no atomics)
__global__ void k_l2(const int* __restrict__ rowstart, const int* __restrict__ csr_src,
                     const float* __restrict__ al_s2, const float* __restrict__ al_d2,
                     const unsigned short* __restrict__ h2bf, const float* __restrict__ b2,
                     float* __restrict__ o2) {
    int n = blockIdx.x * 4 + (threadIdx.x >> 6);
    int lane = threadIdx.x & 63;
    float ald = al_d2[n];
    int start = rowstart[n], end = rowstart[n + 1];
    // pass 1: max, lane-parallel
    float m = -1e30f;
    for (int e = start + lane; e < end; e += 64) {
        m = fmaxf(m, lrelu(al_s2[csr_src[e]] + ald));
    }
    for (int o = 32; o >= 1; o >>= 1) m = fmaxf(m, __shfl_xor(m, o, 64));
    // pass 2: weighted aggregate, 2-edge unroll for load ILP
    float denom = 0.f;
    float acc[8] = {0.f, 0.f, 0.f, 0.f, 0.f, 0.f, 0.f, 0.f};
    int e = start;
    for (; e + 1 < end; e += 2) {
        int s0 = csr_src[e], s1 = csr_src[e + 1];
        float ex0 = __expf(lrelu(al_s2[s0] + ald) - m);
        float ex1 = __expf(lrelu(al_s2[s1] + ald) - m);
        denom += ex0 + ex1;
        uint4 a = *(const uint4*)(h2bf + s0 * 512 + lane * 8);
        uint4 b = *(const uint4*)(h2bf + s1 * 512 + lane * 8);
        acc[0] = fmaf(ex0, bflo(a.x), fmaf(ex1, bflo(b.x), acc[0]));
        acc[1] = fmaf(ex0, bfhi(a.x), fmaf(ex1, bfhi(b.x), acc[1]));
        acc[2] = fmaf(ex0, bflo(a.y), fmaf(ex1, bflo(b.y), acc[2]));
        acc[3] = fmaf(ex0, bfhi(a.y), fmaf(ex1, bfhi(b.y), acc[3]));
        acc[4] = fmaf(ex0, bflo(a.z), fmaf(ex1, bflo(b.z), acc[4]));
        acc[5] = fmaf(ex0, bfhi(a.z), fmaf(ex1, bfhi(b.z), acc[5]));
        acc[6] = fmaf(ex0, bflo(a.w), fmaf(ex1, bflo(b.w), acc[6]));
        acc[7] = fmaf(ex0, bfhi(a.w), fmaf(ex1, bfhi(b.w), acc[7]));
    }
    if (e < end) {
        int s0 = csr_src[e];
        float ex0 = __expf(lrelu(al_s2[s0] + ald) - m);
        denom += ex0;
        uint4 a = *(const uint4*)(h2bf + s0 * 512 + lane * 8);
        acc[0] = fmaf(ex0, bflo(a.x), acc[0]);
        acc[1] = fmaf(ex0, bfhi(a.x), acc[1]);
        acc[2] = fmaf(ex0, bflo(a.y), acc[2]);
        acc[3] = fmaf(ex0, bfhi(a.y), acc[3]);
        acc[4] = fmaf(ex0, bflo(a.z), acc[4]);
        acc[5] = fmaf(ex0, bfhi(a.z), acc[5]);
        acc[6] = fmaf(ex0, bflo(a.w), acc[6]);
        acc[7] = fmaf(ex0, bfhi(a.w), acc[7]);
    }
    float inv = 1.f / denom;
    const float* bp = b2 + lane * 8;
    float4 v0, v1;
    v0.x = elu1(acc[0] * inv + bp[0]);
    v0.y = elu1(acc[1] * inv + bp[1]);
    v0.z = elu1(acc[2] * inv + bp[2]);
    v0.w = elu1(acc[3] * inv + bp[3]);
    v1.x = elu1(acc[4] * inv + bp[4]);
    v1.y = elu1(acc[5] * inv + bp[5]);
    v1.z = elu1(acc[6] * inv + bp[6]);
    v1.w = elu1(acc[7] * inv + bp[7]);
    float* op = o2 + n * 512 + lane * 8;
    *(float4*)op = v0;
    *(float4*)(op + 4) = v1;
}

// segmented mean pool (batch sorted -> contiguous ranges) + final GEMM. No atomics.
__global__ void k_pool_final(const float* __restrict__ o2, const int* __restrict__ gstart,
                             const float* __restrict__ Wo, const float* __restrict__ bo,
                             float* __restrict__ out) {
    __shared__ float sp[512];
    int g = blockIdx.x, j = threadIdx.x;
    int s = gstart[g], e = gstart[g + 1];
    float v = 0.f;
    for (int n = s; n < e; ++n) v += o2[n * 512 + j];
    float c = (float)(e - s);
    c = c > 0.f ? c : 1.f;
    sp[j] = v / c;
    __syncthreads();
    float acc = bo[j];
    for (int k = 0; k < 512; ++k) acc = fmaf(sp[k], Wo[k * 512 + j], acc);
    out[g * 512 + j] = acc;
}

extern "C" void kernel_launch(void* const* d_in, const int* in_sizes, int n_in,
                              void* d_out, int out_size, void* d_ws, size_t ws_size,
                              hipStream_t stream) {
    const float* x     = (const float*)d_in[0];
    const int*   ei    = (const int*)d_in[1];    // [2, NE]
    const int*   batch = (const int*)d_in[2];    // [NN] sorted
    const float* W1    = (const float*)d_in[3];
    const float* as1   = (const float*)d_in[4];
    const float* ad1   = (const float*)d_in[5];
    const float* b1    = (const float*)d_in[6];
    const float* W2    = (const float*)d_in[7];
    const float* as2   = (const float*)d_in[8];
    const float* ad2   = (const float*)d_in[9];
    const float* b2    = (const float*)d_in[10];
    const float* Wo    = (const float*)d_in[11];
    const float* bo    = (const float*)d_in[12];
    float* out = (float*)d_out;

    // ---- workspace arena (4-byte units) ----
    float* w = (float*)d_ws;
    unsigned short* h1bf = (unsigned short*)(w + 0);        // NN*64 ushort = 640,000 units
    float* al_s1 = w + 640000;    // 160,000
    float* al_d1 = w + 800000;    // 160,000
    float* o1    = w + 960000;    // 1,280,000
    unsigned short* h2bf = (unsigned short*)(w + 2240000);  // NN*512 ushort = 5,120,000 units
    float* al_s2 = w + 7360000;   // 20,000
    float* al_d2 = w + 7380000;   // 20,000
    float* o2    = w + 7400000;   // 10,240,000 (byte 29,600,000: 16B aligned)
    int*   rowstart = (int*)(w + 17640000);  // 20,001
    int*   cursor   = (int*)(w + 17660004);  // 20,000
    int*   csr_src  = (int*)(w + 17680004);  // 340,000
    int*   gstart   = (int*)(w + 18020004);  // 65
    // ---- zero-initialized region ----
    int*   deg      = (int*)(w + 18020072);  // 20,000
    // end: 18,040,072 units ≈ 72.2 MB

    hipMemsetAsync(w + 18020072, 0, (size_t)20000 * 4, stream);

    k_hist   <<<(NT + 255) / 256, 256, 0, stream>>>(ei, deg);
    k_scan   <<<1, 1024, 0, stream>>>(deg, batch, rowstart, cursor, gstart);
    k_scatter<<<(NT + 255) / 256, 256, 0, stream>>>(ei, cursor, csr_src);

    k1_h1    <<<NN / 4, 256, 0, stream>>>(x, W1, as1, ad1, h1bf, al_s1, al_d1);
    k_l1     <<<NN / 4, 256, 0, stream>>>(rowstart, csr_src, al_s1, al_d1, h1bf, b1, o1);
    k5b_h2   <<<NN / 16, 512, 0, stream>>>(o1, W2, h2bf);
    k5c_logits<<<NN / 4, 256, 0, stream>>>(h2bf, as2, ad2, al_s2, al_d2);
    k_l2     <<<NN / 4, 256, 0, stream>>>(rowstart, csr_src, al_s2, al_d2, h2bf, b2, o2);

    k_pool_final<<<NG, 512, 0, stream>>>(o2, gstart, Wo, bo, out);
}

// Round 6
// 299.578 us; speedup vs baseline: 2.2903x; 1.1875x over previous
//
#include <hip/hip_runtime.h>
#include <math.h>

#define NN 20000      // nodes
#define NE 320000     // edges (without self loops)
#define NT 340000     // edges + self loops
#define NG 64         // graphs

__device__ __forceinline__ float lrelu(float v) { return v > 0.f ? v : 0.2f * v; }
__device__ __forceinline__ float elu1(float v)  { return v > 0.f ? v : (expf(v) - 1.f); }
__device__ __forceinline__ float bflo(unsigned u) { return __uint_as_float(u << 16); }
__device__ __forceinline__ float bfhi(unsigned u) { return __uint_as_float(u & 0xFFFF0000u); }
__device__ __forceinline__ unsigned short f2bf(float f) {
    unsigned u = __float_as_uint(f);
    u += 0x7FFFu + ((u >> 16) & 1u);   // round to nearest even
    return (unsigned short)(u >> 16);
}

__device__ __forceinline__ int esrc(const int* ei, int e) { return e < NE ? ei[e] : (e - NE); }
__device__ __forceinline__ int edst(const int* ei, int e) { return e < NE ? ei[NE + e] : (e - NE); }

// ---------- CSR build (by dst) ----------
__global__ void k_hist(const int* __restrict__ ei, int* __restrict__ deg) {
    int t = blockIdx.x * blockDim.x + threadIdx.x;
    if (t >= NT) return;
    atomicAdd(&deg[edst(ei, t)], 1);
}

// single-block: exclusive scan of deg -> rowstart/cursor; binary-search gstart from sorted batch
__global__ void k_scan(const int* __restrict__ deg, const int* __restrict__ batch,
                       int* __restrict__ rowstart, int* __restrict__ cursor,
                       int* __restrict__ gstart) {
    __shared__ int part[1024];
    int t = threadIdx.x;
    int base = t * 20;
    int local[20];
    int s = 0;
    if (base < NN) {
#pragma unroll
        for (int i = 0; i < 20; ++i) { local[i] = deg[base + i]; s += local[i]; }
    }
    part[t] = s;
    __syncthreads();
    for (int o = 1; o < 1024; o <<= 1) {
        int v = (t >= o) ? part[t - o] : 0;
        __syncthreads();
        part[t] += v;
        __syncthreads();
    }
    if (base < NN) {
        int run = (t == 0) ? 0 : part[t - 1];
#pragma unroll
        for (int i = 0; i < 20; ++i) {
            rowstart[base + i] = run;
            cursor[base + i] = run;
            run += local[i];
        }
    }
    if (t == 1023) rowstart[NN] = part[1023];
    if (t <= NG) {  // gstart[t] = first node with batch >= t (batch sorted)
        int lo = 0, hi = NN;
        while (lo < hi) {
            int mid = (lo + hi) >> 1;
            if (batch[mid] < t) lo = mid + 1; else hi = mid;
        }
        gstart[t] = lo;
    }
}

__global__ void k_scatter(const int* __restrict__ ei, int* __restrict__ cursor,
                          int* __restrict__ csr_src) {
    int t = blockIdx.x * blockDim.x + threadIdx.x;
    if (t >= NT) return;
    int d = edst(ei, t), s = esrc(ei, t);
    int pos = atomicAdd(&cursor[d], 1);
    csr_src[pos] = s;
}

// ---------- layer 1 ----------
__global__ void k1_h1(const float* __restrict__ x, const float* __restrict__ W1,
                      const float* __restrict__ as1, const float* __restrict__ ad1,
                      unsigned short* __restrict__ h1bf, float* __restrict__ al_s,
                      float* __restrict__ al_d) {
    int n = blockIdx.x * 4 + (threadIdx.x >> 6);
    int j = threadIdx.x & 63;
    float x0 = x[n * 3 + 0], x1 = x[n * 3 + 1], x2 = x[n * 3 + 2];
    float v = fmaf(x0, W1[j], fmaf(x1, W1[64 + j], x2 * W1[128 + j]));
    h1bf[n * 64 + j] = f2bf(v);
    float ps = v * as1[j];
    float pd = v * ad1[j];
    for (int o = 4; o >= 1; o >>= 1) {
        ps += __shfl_xor(ps, o, 8);
        pd += __shfl_xor(pd, o, 8);
    }
    if ((j & 7) == 0) {
        al_s[n * 8 + (j >> 3)] = ps;
        al_d[n * 8 + (j >> 3)] = pd;
    }
}

// fused layer-1 softmax + aggregate + bias + elu. 1 wave per node, lane = channel.
__global__ void k_l1(const int* __restrict__ rowstart, const int* __restrict__ csr_src,
                     const float* __restrict__ al_s, const float* __restrict__ al_d,
                     const unsigned short* __restrict__ h1bf, const float* __restrict__ b1,
                     float* __restrict__ o1) {
    int n = blockIdx.x * 4 + (threadIdx.x >> 6);
    int j = threadIdx.x & 63;  // channel
    int h = j >> 3;            // head
    float ald = al_d[n * 8 + h];
    int start = rowstart[n], end = rowstart[n + 1];
    float m = -1e30f;
    for (int e = start + (j & 7); e < end; e += 8) {
        m = fmaxf(m, lrelu(al_s[csr_src[e] * 8 + h] + ald));
    }
    for (int o = 4; o >= 1; o >>= 1) m = fmaxf(m, __shfl_xor(m, o, 8));
    float denom = 0.f, acc = 0.f;
    for (int e = start; e < end; ++e) {
        int s = csr_src[e];
        float ex = __expf(lrelu(al_s[s * 8 + h] + ald) - m);
        denom += ex;
        float hv = __uint_as_float(((unsigned)h1bf[s * 64 + j]) << 16);
        acc = fmaf(ex, hv, acc);
    }
    o1[n * 64 + j] = elu1(acc / denom + b1[j]);
}

// h2bf = bf16(o1 @ W2), tiled 16 nodes/block so W2 stays in L2
__global__ void k5b_h2(const float* __restrict__ o1, const float* __restrict__ W2,
                       unsigned short* __restrict__ h2bf) {
    __shared__ float sO[16][64];
    int n0 = blockIdx.x * 16;
    int j = threadIdx.x;  // 512
    for (int i = j; i < 1024; i += 512) sO[i >> 6][i & 63] = o1[n0 * 64 + i];
    __syncthreads();
    float acc[16];
#pragma unroll
    for (int i = 0; i < 16; ++i) acc[i] = 0.f;
    for (int k = 0; k < 64; ++k) {
        float wv = W2[k * 512 + j];
#pragma unroll
        for (int i = 0; i < 16; ++i) acc[i] = fmaf(sO[i][k], wv, acc[i]);
    }
#pragma unroll
    for (int i = 0; i < 16; ++i) h2bf[(n0 + i) * 512 + j] = f2bf(acc[i]);
}

// al_s2/al_d2[n] = dot(h2[n], a2).  one wave per node.
__global__ void k5c_logits(const unsigned short* __restrict__ h2bf,
                           const float* __restrict__ as2, const float* __restrict__ ad2,
                           float* __restrict__ al_s2, float* __restrict__ al_d2) {
    int w = threadIdx.x >> 6, lane = threadIdx.x & 63;
    int n = blockIdx.x * 4 + w;
    uint4 hv = *(const uint4*)(h2bf + n * 512 + lane * 8);
    const float4* sp = (const float4*)(as2 + lane * 8);
    const float4* dp = (const float4*)(ad2 + lane * 8);
    float4 s0 = sp[0], s1 = sp[1];
    float4 d0 = dp[0], d1 = dp[1];
    float f0 = bflo(hv.x), f1 = bfhi(hv.x), f2 = bflo(hv.y), f3 = bfhi(hv.y);
    float f4 = bflo(hv.z), f5 = bfhi(hv.z), f6 = bflo(hv.w), f7 = bfhi(hv.w);
    float ps = f0 * s0.x + f1 * s0.y + f2 * s0.z + f3 * s0.w
             + f4 * s1.x + f5 * s1.y + f6 * s1.z + f7 * s1.w;
    float pd = f0 * d0.x + f1 * d0.y + f2 * d0.z + f3 * d0.w
             + f4 * d1.x + f5 * d1.y + f6 * d1.z + f7 * d1.w;
    for (int o = 32; o >= 1; o >>= 1) {
        ps += __shfl_xor(ps, o, 64);
        pd += __shfl_xor(pd, o, 64);
    }
    if (lane == 0) { al_s2[n] = ps; al_d2[n] = pd; }
}

// fused layer-2 softmax + aggregate + bias + elu -> o2 (plain coalesced stores, no atomics)
__global__ void k_l2(const int* __restrict__ rowstart, const int* __restrict__ csr_src,
                     const float* __restrict__ al_s2, const float* __restrict__ al_d2,
                     const unsigned short* __restrict__ h2bf, const float* __restrict__ b2,
                     float* __restrict__ o2) {
    int n = blockIdx.x * 4 + (threadIdx.x >> 6);
    int lane = threadIdx.x & 63;
    float ald = al_d2[n];
    int start = rowstart[n], end = rowstart[n + 1];
    // pass 1: max, lane-parallel
    float m = -1e30f;
    for (int e = start + lane; e < end; e += 64) {
        m = fmaxf(m, lrelu(al_s2[csr_src[e]] + ald));
    }
    for (int o = 32; o >= 1; o >>= 1) m = fmaxf(m, __shfl_xor(m, o, 64));
    // pass 2: weighted aggregate, 2-edge unroll for load ILP
    float denom = 0.f;
    float acc[8] = {0.f, 0.f, 0.f, 0.f, 0.f, 0.f, 0.f, 0.f};
    int e = start;
    for (; e + 1 < end; e += 2) {
        int s0 = csr_src[e], s1 = csr_src[e + 1];
        float ex0 = __expf(lrelu(al_s2[s0] + ald) - m);
        float ex1 = __expf(lrelu(al_s2[s1] + ald) - m);
        denom += ex0 + ex1;
        uint4 a = *(const uint4*)(h2bf + s0 * 512 + lane * 8);
        uint4 b = *(const uint4*)(h2bf + s1 * 512 + lane * 8);
        acc[0] = fmaf(ex0, bflo(a.x), fmaf(ex1, bflo(b.x), acc[0]));
        acc[1] = fmaf(ex0, bfhi(a.x), fmaf(ex1, bfhi(b.x), acc[1]));
        acc[2] = fmaf(ex0, bflo(a.y), fmaf(ex1, bflo(b.y), acc[2]));
        acc[3] = fmaf(ex0, bfhi(a.y), fmaf(ex1, bfhi(b.y), acc[3]));
        acc[4] = fmaf(ex0, bflo(a.z), fmaf(ex1, bflo(b.z), acc[4]));
        acc[5] = fmaf(ex0, bfhi(a.z), fmaf(ex1, bfhi(b.z), acc[5]));
        acc[6] = fmaf(ex0, bflo(a.w), fmaf(ex1, bflo(b.w), acc[6]));
        acc[7] = fmaf(ex0, bfhi(a.w), fmaf(ex1, bfhi(b.w), acc[7]));
    }
    if (e < end) {
        int s0 = csr_src[e];
        float ex0 = __expf(lrelu(al_s2[s0] + ald) - m);
        denom += ex0;
        uint4 a = *(const uint4*)(h2bf + s0 * 512 + lane * 8);
        acc[0] = fmaf(ex0, bflo(a.x), acc[0]);
        acc[1] = fmaf(ex0, bfhi(a.x), acc[1]);
        acc[2] = fmaf(ex0, bflo(a.y), acc[2]);
        acc[3] = fmaf(ex0, bfhi(a.y), acc[3]);
        acc[4] = fmaf(ex0, bflo(a.z), acc[4]);
        acc[5] = fmaf(ex0, bfhi(a.z), acc[5]);
        acc[6] = fmaf(ex0, bflo(a.w), acc[6]);
        acc[7] = fmaf(ex0, bfhi(a.w), acc[7]);
    }
    float inv = 1.f / denom;
    const float* bp = b2 + lane * 8;
    float4 v0, v1;
    v0.x = elu1(acc[0] * inv + bp[0]);
    v0.y = elu1(acc[1] * inv + bp[1]);
    v0.z = elu1(acc[2] * inv + bp[2]);
    v0.w = elu1(acc[3] * inv + bp[3]);
    v1.x = elu1(acc[4] * inv + bp[4]);
    v1.y = elu1(acc[5] * inv + bp[5]);
    v1.z = elu1(acc[6] * inv + bp[6]);
    v1.w = elu1(acc[7] * inv + bp[7]);
    float* op = o2 + n * 512 + lane * 8;
    *(float4*)op = v0;
    *(float4*)(op + 4) = v1;
}

// segmented mean pool, parallel: block = (graph g, 64-channel chunk c). 4 waves stride nodes.
__global__ void k_pool(const float* __restrict__ o2, const int* __restrict__ gstart,
                       float* __restrict__ pooled) {
    __shared__ float red[4][64];
    int g = blockIdx.x >> 3;
    int c = (blockIdx.x & 7) * 64;
    int w = threadIdx.x >> 6, lane = threadIdx.x & 63;
    int s = gstart[g], e = gstart[g + 1];
    float acc = 0.f;
    for (int n = s + w; n < e; n += 4) acc += o2[n * 512 + c + lane];
    red[w][lane] = acc;
    __syncthreads();
    if (w == 0) {
        float v = red[0][lane] + red[1][lane] + red[2][lane] + red[3][lane];
        float cf = (float)(e - s);
        cf = cf > 0.f ? cf : 1.f;
        pooled[g * 512 + c + lane] = v / cf;
    }
}

// final GEMM: out[g][j] = pooled[g] @ Wo[:,j] + bo[j].  block = (g, 64-col chunk).
__global__ void k_final(const float* __restrict__ pooled, const float* __restrict__ Wo,
                        const float* __restrict__ bo, float* __restrict__ out) {
    __shared__ float sp[512];
    int g = blockIdx.x >> 3;
    int j = (blockIdx.x & 7) * 64 + threadIdx.x;  // 64 threads
    for (int k = threadIdx.x; k < 512; k += 64) sp[k] = pooled[g * 512 + k];
    __syncthreads();
    float acc = bo[j];
    for (int k = 0; k < 512; ++k) acc = fmaf(sp[k], Wo[k * 512 + j], acc);
    out[g * 512 + j] = acc;
}

extern "C" void kernel_launch(void* const* d_in, const int* in_sizes, int n_in,
                              void* d_out, int out_size, void* d_ws, size_t ws_size,
                              hipStream_t stream) {
    const float* x     = (const float*)d_in[0];
    const int*   ei    = (const int*)d_in[1];    // [2, NE]
    const int*   batch = (const int*)d_in[2];    // [NN] sorted
    const float* W1    = (const float*)d_in[3];
    const float* as1   = (const float*)d_in[4];
    const float* ad1   = (const float*)d_in[5];
    const float* b1    = (const float*)d_in[6];
    const float* W2    = (const float*)d_in[7];
    const float* as2   = (const float*)d_in[8];
    const float* ad2   = (const float*)d_in[9];
    const float* b2    = (const float*)d_in[10];
    const float* Wo    = (const float*)d_in[11];
    const float* bo    = (const float*)d_in[12];
    float* out = (float*)d_out;

    // ---- workspace arena (4-byte units) ----
    float* w = (float*)d_ws;
    unsigned short* h1bf = (unsigned short*)(w + 0);        // NN*64 ushort = 640,000 units
    float* al_s1 = w + 640000;    // 160,000
    float* al_d1 = w + 800000;    // 160,000
    float* o1    = w + 960000;    // 1,280,000
    unsigned short* h2bf = (unsigned short*)(w + 2240000);  // NN*512 ushort = 5,120,000 units
    float* al_s2 = w + 7360000;   // 20,000
    float* al_d2 = w + 7380000;   // 20,000
    float* o2    = w + 7400000;   // 10,240,000 (byte 29,600,000: 16B aligned)
    int*   rowstart = (int*)(w + 17640000);  // 20,001
    int*   cursor   = (int*)(w + 17660004);  // 20,000
    int*   csr_src  = (int*)(w + 17680004);  // 340,000
    int*   gstart   = (int*)(w + 18020004);  // 65
    float* pooled   = w + 18020072;          // 32,768
    // ---- zero-initialized region ----
    int*   deg      = (int*)(w + 18052840);  // 20,000
    // end: 18,072,840 units ≈ 72.3 MB

    hipMemsetAsync(w + 18052840, 0, (size_t)20000 * 4, stream);

    k_hist   <<<(NT + 255) / 256, 256, 0, stream>>>(ei, deg);
    k_scan   <<<1, 1024, 0, stream>>>(deg, batch, rowstart, cursor, gstart);
    k_scatter<<<(NT + 255) / 256, 256, 0, stream>>>(ei, cursor, csr_src);

    k1_h1    <<<NN / 4, 256, 0, stream>>>(x, W1, as1, ad1, h1bf, al_s1, al_d1);
    k_l1     <<<NN / 4, 256, 0, stream>>>(rowstart, csr_src, al_s1, al_d1, h1bf, b1, o1);
    k5b_h2   <<<NN / 16, 512, 0, stream>>>(o1, W2, h2bf);
    k5c_logits<<<NN / 4, 256, 0, stream>>>(h2bf, as2, ad2, al_s2, al_d2);
    k_l2     <<<NN / 4, 256, 0, stream>>>(rowstart, csr_src, al_s2, al_d2, h2bf, b2, o2);

    k_pool   <<<NG * 8, 256, 0, stream>>>(o2, gstart, pooled);
    k_final  <<<NG * 8, 64, 0, stream>>>(pooled, Wo, bo, out);
}

// Round 7
// 276.077 us; speedup vs baseline: 2.4852x; 1.0851x over previous
//
#include <hip/hip_runtime.h>
#include <math.h>

#define NN 20000      // nodes
#define NE 320000     // edges (without self loops)
#define NT 340000     // edges + self loops
#define NG 64         // graphs
#define HB 1329       // (NT+255)/256 hist blocks

__device__ __forceinline__ float lrelu(float v) { return v > 0.f ? v : 0.2f * v; }
__device__ __forceinline__ float elu1(float v)  { return v > 0.f ? v : (expf(v) - 1.f); }
__device__ __forceinline__ float bflo(unsigned u) { return __uint_as_float(u << 16); }
__device__ __forceinline__ float bfhi(unsigned u) { return __uint_as_float(u & 0xFFFF0000u); }
__device__ __forceinline__ unsigned short f2bf(float f) {
    unsigned u = __float_as_uint(f);
    u += 0x7FFFu + ((u >> 16) & 1u);   // round to nearest even
    return (unsigned short)(u >> 16);
}

__device__ __forceinline__ int esrc(const int* ei, int e) { return e < NE ? ei[e] : (e - NE); }
__device__ __forceinline__ int edst(const int* ei, int e) { return e < NE ? ei[NE + e] : (e - NE); }

// ---------- fused: CSR degree histogram (blocks 0..HB-1) + layer-1 transform (rest) ----------
__global__ void k_hist_h1(const int* __restrict__ ei, int* __restrict__ deg,
                          const float* __restrict__ x, const float* __restrict__ W1,
                          const float* __restrict__ as1, const float* __restrict__ ad1,
                          unsigned short* __restrict__ h1bf, float* __restrict__ al_s,
                          float* __restrict__ al_d) {
    if (blockIdx.x < HB) {
        int t = blockIdx.x * 256 + threadIdx.x;
        if (t < NT) atomicAdd(&deg[edst(ei, t)], 1);
        return;
    }
    int n = (blockIdx.x - HB) * 4 + (threadIdx.x >> 6);
    int j = threadIdx.x & 63;
    float x0 = x[n * 3 + 0], x1 = x[n * 3 + 1], x2 = x[n * 3 + 2];
    float v = fmaf(x0, W1[j], fmaf(x1, W1[64 + j], x2 * W1[128 + j]));
    h1bf[n * 64 + j] = f2bf(v);
    float ps = v * as1[j];
    float pd = v * ad1[j];
    for (int o = 4; o >= 1; o >>= 1) {
        ps += __shfl_xor(ps, o, 8);
        pd += __shfl_xor(pd, o, 8);
    }
    if ((j & 7) == 0) {
        al_s[n * 8 + (j >> 3)] = ps;
        al_d[n * 8 + (j >> 3)] = pd;
    }
}

// single-block: exclusive scan of deg -> rowstart/cursor; binary-search gstart from sorted batch
__global__ void k_scan(const int* __restrict__ deg, const int* __restrict__ batch,
                       int* __restrict__ rowstart, int* __restrict__ cursor,
                       int* __restrict__ gstart) {
    __shared__ int part[1024];
    int t = threadIdx.x;
    int base = t * 20;
    int local[20];
    int s = 0;
    if (base < NN) {
#pragma unroll
        for (int i = 0; i < 20; ++i) { local[i] = deg[base + i]; s += local[i]; }
    }
    part[t] = s;
    __syncthreads();
    for (int o = 1; o < 1024; o <<= 1) {
        int v = (t >= o) ? part[t - o] : 0;
        __syncthreads();
        part[t] += v;
        __syncthreads();
    }
    if (base < NN) {
        int run = (t == 0) ? 0 : part[t - 1];
#pragma unroll
        for (int i = 0; i < 20; ++i) {
            rowstart[base + i] = run;
            cursor[base + i] = run;
            run += local[i];
        }
    }
    if (t == 1023) rowstart[NN] = part[1023];
    if (t <= NG) {  // gstart[t] = first node with batch >= t (batch sorted)
        int lo = 0, hi = NN;
        while (lo < hi) {
            int mid = (lo + hi) >> 1;
            if (batch[mid] < t) lo = mid + 1; else hi = mid;
        }
        gstart[t] = lo;
    }
}

__global__ void k_scatter(const int* __restrict__ ei, int* __restrict__ cursor,
                          int* __restrict__ csr_src) {
    int t = blockIdx.x * blockDim.x + threadIdx.x;
    if (t >= NT) return;
    int d = edst(ei, t), s = esrc(ei, t);
    int pos = atomicAdd(&cursor[d], 1);
    csr_src[pos] = s;
}

// fused layer-1 softmax + aggregate + bias + elu. 1 wave per node, lane = channel.
__global__ void k_l1(const int* __restrict__ rowstart, const int* __restrict__ csr_src,
                     const float* __restrict__ al_s, const float* __restrict__ al_d,
                     const unsigned short* __restrict__ h1bf, const float* __restrict__ b1,
                     float* __restrict__ o1) {
    int n = blockIdx.x * 4 + (threadIdx.x >> 6);
    int j = threadIdx.x & 63;  // channel
    int h = j >> 3;            // head
    float ald = al_d[n * 8 + h];
    int start = rowstart[n], end = rowstart[n + 1];
    float m = -1e30f;
    for (int e = start + (j & 7); e < end; e += 8) {
        m = fmaxf(m, lrelu(al_s[csr_src[e] * 8 + h] + ald));
    }
    for (int o = 4; o >= 1; o >>= 1) m = fmaxf(m, __shfl_xor(m, o, 8));
    float denom = 0.f, acc = 0.f;
    int e = start;
    for (; e + 1 < end; e += 2) {
        int s0 = csr_src[e], s1 = csr_src[e + 1];
        float ex0 = __expf(lrelu(al_s[s0 * 8 + h] + ald) - m);
        float ex1 = __expf(lrelu(al_s[s1 * 8 + h] + ald) - m);
        denom += ex0 + ex1;
        float hv0 = __uint_as_float(((unsigned)h1bf[s0 * 64 + j]) << 16);
        float hv1 = __uint_as_float(((unsigned)h1bf[s1 * 64 + j]) << 16);
        acc = fmaf(ex0, hv0, fmaf(ex1, hv1, acc));
    }
    if (e < end) {
        int s0 = csr_src[e];
        float ex0 = __expf(lrelu(al_s[s0 * 8 + h] + ald) - m);
        denom += ex0;
        acc = fmaf(ex0, __uint_as_float(((unsigned)h1bf[s0 * 64 + j]) << 16), acc);
    }
    o1[n * 64 + j] = elu1(acc / denom + b1[j]);
}

// h2bf = bf16(o1 @ W2), 16 nodes/block; fused layer-2 attention logits (from f32 acc)
__global__ void k5b_h2(const float* __restrict__ o1, const float* __restrict__ W2,
                       const float* __restrict__ as2, const float* __restrict__ ad2,
                       unsigned short* __restrict__ h2bf, float* __restrict__ al_s2,
                       float* __restrict__ al_d2) {
    __shared__ float sO[16][64];
    __shared__ float redS[16][8], redD[16][8];
    int n0 = blockIdx.x * 16;
    int j = threadIdx.x;  // 512
    int w = j >> 6, lane = j & 63;
    for (int i = j; i < 1024; i += 512) sO[i >> 6][i & 63] = o1[n0 * 64 + i];
    __syncthreads();
    float acc[16];
#pragma unroll
    for (int i = 0; i < 16; ++i) acc[i] = 0.f;
    for (int k = 0; k < 64; ++k) {
        float wv = W2[k * 512 + j];
#pragma unroll
        for (int i = 0; i < 16; ++i) acc[i] = fmaf(sO[i][k], wv, acc[i]);
    }
    float a_s = as2[j], a_d = ad2[j];
#pragma unroll
    for (int i = 0; i < 16; ++i) {
        h2bf[(n0 + i) * 512 + j] = f2bf(acc[i]);
        float ps = acc[i] * a_s;
        float pd = acc[i] * a_d;
        for (int o = 32; o >= 1; o >>= 1) {
            ps += __shfl_xor(ps, o, 64);
            pd += __shfl_xor(pd, o, 64);
        }
        if (lane == 0) { redS[i][w] = ps; redD[i][w] = pd; }
    }
    __syncthreads();
    if (j < 16) {
        float s = 0.f;
#pragma unroll
        for (int i = 0; i < 8; ++i) s += redS[j][i];
        al_s2[n0 + j] = s;
    } else if (j < 32) {
        int i0 = j - 16;
        float s = 0.f;
#pragma unroll
        for (int i = 0; i < 8; ++i) s += redD[i0][i];
        al_d2[n0 + i0] = s;
    }
}

// fused layer-2 softmax + aggregate + bias + elu + block-level mean-pool reduction.
// 1 wave per node; lane owns 8 channels; block reduces 4 nodes -> atomics into sums.
__global__ void k_l2(const int* __restrict__ rowstart, const int* __restrict__ csr_src,
                     const float* __restrict__ al_s2, const float* __restrict__ al_d2,
                     const unsigned short* __restrict__ h2bf, const float* __restrict__ b2,
                     const int* __restrict__ batch, float* __restrict__ sums) {
    __shared__ float ld[4][512];
    int n0 = blockIdx.x * 4;
    int w = threadIdx.x >> 6, lane = threadIdx.x & 63;
    int n = n0 + w;
    float ald = al_d2[n];
    int start = rowstart[n], end = rowstart[n + 1];
    // pass 1: max, lane-parallel
    float m = -1e30f;
    for (int e = start + lane; e < end; e += 64) {
        m = fmaxf(m, lrelu(al_s2[csr_src[e]] + ald));
    }
    for (int o = 32; o >= 1; o >>= 1) m = fmaxf(m, __shfl_xor(m, o, 64));
    // pass 2: weighted aggregate, 2-edge unroll
    float denom = 0.f;
    float acc[8] = {0.f, 0.f, 0.f, 0.f, 0.f, 0.f, 0.f, 0.f};
    int e = start;
    for (; e + 1 < end; e += 2) {
        int s0 = csr_src[e], s1 = csr_src[e + 1];
        float ex0 = __expf(lrelu(al_s2[s0] + ald) - m);
        float ex1 = __expf(lrelu(al_s2[s1] + ald) - m);
        denom += ex0 + ex1;
        uint4 a = *(const uint4*)(h2bf + s0 * 512 + lane * 8);
        uint4 b = *(const uint4*)(h2bf + s1 * 512 + lane * 8);
        acc[0] = fmaf(ex0, bflo(a.x), fmaf(ex1, bflo(b.x), acc[0]));
        acc[1] = fmaf(ex0, bfhi(a.x), fmaf(ex1, bfhi(b.x), acc[1]));
        acc[2] = fmaf(ex0, bflo(a.y), fmaf(ex1, bflo(b.y), acc[2]));
        acc[3] = fmaf(ex0, bfhi(a.y), fmaf(ex1, bfhi(b.y), acc[3]));
        acc[4] = fmaf(ex0, bflo(a.z), fmaf(ex1, bflo(b.z), acc[4]));
        acc[5] = fmaf(ex0, bfhi(a.z), fmaf(ex1, bfhi(b.z), acc[5]));
        acc[6] = fmaf(ex0, bflo(a.w), fmaf(ex1, bflo(b.w), acc[6]));
        acc[7] = fmaf(ex0, bfhi(a.w), fmaf(ex1, bfhi(b.w), acc[7]));
    }
    if (e < end) {
        int s0 = csr_src[e];
        float ex0 = __expf(lrelu(al_s2[s0] + ald) - m);
        denom += ex0;
        uint4 a = *(const uint4*)(h2bf + s0 * 512 + lane * 8);
        acc[0] = fmaf(ex0, bflo(a.x), acc[0]);
        acc[1] = fmaf(ex0, bfhi(a.x), acc[1]);
        acc[2] = fmaf(ex0, bflo(a.y), acc[2]);
        acc[3] = fmaf(ex0, bfhi(a.y), acc[3]);
        acc[4] = fmaf(ex0, bflo(a.z), acc[4]);
        acc[5] = fmaf(ex0, bfhi(a.z), acc[5]);
        acc[6] = fmaf(ex0, bflo(a.w), acc[6]);
        acc[7] = fmaf(ex0, bfhi(a.w), acc[7]);
    }
    float inv = 1.f / denom;
    const float* bp = b2 + lane * 8;
    float4 v0, v1;
    v0.x = elu1(acc[0] * inv + bp[0]);
    v0.y = elu1(acc[1] * inv + bp[1]);
    v0.z = elu1(acc[2] * inv + bp[2]);
    v0.w = elu1(acc[3] * inv + bp[3]);
    v1.x = elu1(acc[4] * inv + bp[4]);
    v1.y = elu1(acc[5] * inv + bp[5]);
    v1.z = elu1(acc[6] * inv + bp[6]);
    v1.w = elu1(acc[7] * inv + bp[7]);
    *(float4*)&ld[w][lane * 8] = v0;
    *(float4*)&ld[w][lane * 8 + 4] = v1;
    __syncthreads();
    // block reduction grouped by graph (batch sorted -> same-g rows contiguous)
    int t = threadIdx.x;  // channels t and t+256
    int g_prev = batch[n0];
    float a0 = 0.f, a1 = 0.f;
#pragma unroll
    for (int wi = 0; wi < 4; ++wi) {
        int gi = batch[n0 + wi];
        if (gi != g_prev) {
            atomicAdd(&sums[g_prev * 512 + t], a0);
            atomicAdd(&sums[g_prev * 512 + 256 + t], a1);
            a0 = a1 = 0.f;
            g_prev = gi;
        }
        a0 += ld[wi][t];
        a1 += ld[wi][t + 256];
    }
    atomicAdd(&sums[g_prev * 512 + t], a0);
    atomicAdd(&sums[g_prev * 512 + 256 + t], a1);
}

// final: out[g][j] = (sums[g] @ Wo[:,j]) / cnt[g] + bo[j].  block = (g, 64-col chunk).
__global__ void k_final(const float* __restrict__ sums, const int* __restrict__ gstart,
                        const float* __restrict__ Wo, const float* __restrict__ bo,
                        float* __restrict__ out) {
    __shared__ float sp[512];
    int g = blockIdx.x >> 3;
    int j = (blockIdx.x & 7) * 64 + threadIdx.x;  // 64 threads
    for (int k = threadIdx.x; k < 512; k += 64) sp[k] = sums[g * 512 + k];
    __syncthreads();
    float c = (float)(gstart[g + 1] - gstart[g]);
    float inv = 1.f / (c > 0.f ? c : 1.f);
    float acc = 0.f;
    for (int k = 0; k < 512; ++k) acc = fmaf(sp[k], Wo[k * 512 + j], acc);
    out[g * 512 + j] = fmaf(acc, inv, bo[j]);
}

extern "C" void kernel_launch(void* const* d_in, const int* in_sizes, int n_in,
                              void* d_out, int out_size, void* d_ws, size_t ws_size,
                              hipStream_t stream) {
    const float* x     = (const float*)d_in[0];
    const int*   ei    = (const int*)d_in[1];    // [2, NE]
    const int*   batch = (const int*)d_in[2];    // [NN] sorted
    const float* W1    = (const float*)d_in[3];
    const float* as1   = (const float*)d_in[4];
    const float* ad1   = (const float*)d_in[5];
    const float* b1    = (const float*)d_in[6];
    const float* W2    = (const float*)d_in[7];
    const float* as2   = (const float*)d_in[8];
    const float* ad2   = (const float*)d_in[9];
    const float* b2    = (const float*)d_in[10];
    const float* Wo    = (const float*)d_in[11];
    const float* bo    = (const float*)d_in[12];
    float* out = (float*)d_out;

    // ---- workspace arena (4-byte units) ----
    float* w = (float*)d_ws;
    unsigned short* h1bf = (unsigned short*)(w + 0);        // NN*64 ushort = 640,000 units
    float* al_s1 = w + 640000;    // 160,000
    float* al_d1 = w + 800000;    // 160,000
    float* o1    = w + 960000;    // 1,280,000
    unsigned short* h2bf = (unsigned short*)(w + 2240000);  // NN*512 ushort = 5,120,000 units (byte 8,960,000: 16B aligned)
    float* al_s2 = w + 7360000;   // 20,000
    float* al_d2 = w + 7380000;   // 20,000
    int*   rowstart = (int*)(w + 7400000);   // 20,001
    int*   cursor   = (int*)(w + 7420004);   // 20,000
    int*   csr_src  = (int*)(w + 7440004);   // 340,000
    int*   gstart   = (int*)(w + 7780004);   // 65
    // ---- zero-initialized region ----
    int*   deg  = (int*)(w + 7780072);       // 20,000
    float* sums = w + 7800072;               // 32,768
    // end: 7,832,840 units ≈ 31.3 MB

    hipMemsetAsync(w + 7780072, 0, (size_t)(20000 + 32768) * 4, stream);

    k_hist_h1<<<HB + NN / 4, 256, 0, stream>>>(ei, deg, x, W1, as1, ad1, h1bf, al_s1, al_d1);
    k_scan   <<<1, 1024, 0, stream>>>(deg, batch, rowstart, cursor, gstart);
    k_scatter<<<HB, 256, 0, stream>>>(ei, cursor, csr_src);

    k_l1     <<<NN / 4, 256, 0, stream>>>(rowstart, csr_src, al_s1, al_d1, h1bf, b1, o1);
    k5b_h2   <<<NN / 16, 512, 0, stream>>>(o1, W2, as2, ad2, h2bf, al_s2, al_d2);
    k_l2     <<<NN / 4, 256, 0, stream>>>(rowstart, csr_src, al_s2, al_d2, h2bf, b2, batch, sums);

    k_final  <<<NG * 8, 64, 0, stream>>>(sums, gstart, Wo, bo, out);
}

// Round 8
// 247.926 us; speedup vs baseline: 2.7674x; 1.1135x over previous
//
#include <hip/hip_runtime.h>
#include <math.h>

#define NN 20000      // nodes
#define NE 320000     // edges (without self loops)
#define NT 340000     // edges + self loops
#define NG 64         // graphs
#define HB 1329       // (NT+255)/256 hist blocks
#define CB 128        // W2->bf16 transpose blocks (32768/256)

using short8  = __attribute__((ext_vector_type(8))) short;   // 8 x bf16 (4 VGPRs)
using float4v = __attribute__((ext_vector_type(4))) float;   // MFMA accumulator

__device__ __forceinline__ float lrelu(float v) { return v > 0.f ? v : 0.2f * v; }
__device__ __forceinline__ float elu1(float v)  { return v > 0.f ? v : (expf(v) - 1.f); }
__device__ __forceinline__ float bflo(unsigned u) { return __uint_as_float(u << 16); }
__device__ __forceinline__ float bfhi(unsigned u) { return __uint_as_float(u & 0xFFFF0000u); }
__device__ __forceinline__ unsigned short f2bf(float f) {
    unsigned u = __float_as_uint(f);
    u += 0x7FFFu + ((u >> 16) & 1u);   // round to nearest even
    return (unsigned short)(u >> 16);
}

__device__ __forceinline__ int esrc(const int* ei, int e) { return e < NE ? ei[e] : (e - NE); }
__device__ __forceinline__ int edst(const int* ei, int e) { return e < NE ? ei[NE + e] : (e - NE); }

// ---------- fused: CSR histogram | W2 transpose->bf16 | layer-1 transform ----------
__global__ void k_hist_h1(const int* __restrict__ ei, int* __restrict__ deg,
                          const float* __restrict__ W2, unsigned short* __restrict__ W2bfT,
                          const float* __restrict__ x, const float* __restrict__ W1,
                          const float* __restrict__ as1, const float* __restrict__ ad1,
                          unsigned short* __restrict__ h1bf, float* __restrict__ al_s,
                          float* __restrict__ al_d) {
    if (blockIdx.x < HB) {
        int t = blockIdx.x * 256 + threadIdx.x;
        if (t < NT) atomicAdd(&deg[edst(ei, t)], 1);
        return;
    }
    if (blockIdx.x < HB + CB) {
        int t = (blockIdx.x - HB) * 256 + threadIdx.x;  // t = n*64 + k, 0..32767
        int k = t & 63, n = t >> 6;
        W2bfT[t] = f2bf(W2[k * 512 + n]);
        return;
    }
    int n = (blockIdx.x - HB - CB) * 4 + (threadIdx.x >> 6);
    int j = threadIdx.x & 63;
    float x0 = x[n * 3 + 0], x1 = x[n * 3 + 1], x2 = x[n * 3 + 2];
    float v = fmaf(x0, W1[j], fmaf(x1, W1[64 + j], x2 * W1[128 + j]));
    h1bf[n * 64 + j] = f2bf(v);
    float ps = v * as1[j];
    float pd = v * ad1[j];
    for (int o = 4; o >= 1; o >>= 1) {
        ps += __shfl_xor(ps, o, 8);
        pd += __shfl_xor(pd, o, 8);
    }
    if ((j & 7) == 0) {
        al_s[n * 8 + (j >> 3)] = ps;
        al_d[n * 8 + (j >> 3)] = pd;
    }
}

// single-block: exclusive scan of deg -> rowstart/cursor; binary-search gstart from sorted batch
__global__ void k_scan(const int* __restrict__ deg, const int* __restrict__ batch,
                       int* __restrict__ rowstart, int* __restrict__ cursor,
                       int* __restrict__ gstart) {
    __shared__ int part[1024];
    int t = threadIdx.x;
    int base = t * 20;
    int local[20];
    int s = 0;
    if (base < NN) {
#pragma unroll
        for (int i = 0; i < 20; ++i) { local[i] = deg[base + i]; s += local[i]; }
    }
    part[t] = s;
    __syncthreads();
    for (int o = 1; o < 1024; o <<= 1) {
        int v = (t >= o) ? part[t - o] : 0;
        __syncthreads();
        part[t] += v;
        __syncthreads();
    }
    if (base < NN) {
        int run = (t == 0) ? 0 : part[t - 1];
#pragma unroll
        for (int i = 0; i < 20; ++i) {
            rowstart[base + i] = run;
            cursor[base + i] = run;
            run += local[i];
        }
    }
    if (t == 1023) rowstart[NN] = part[1023];
    if (t <= NG) {
        int lo = 0, hi = NN;
        while (lo < hi) {
            int mid = (lo + hi) >> 1;
            if (batch[mid] < t) lo = mid + 1; else hi = mid;
        }
        gstart[t] = lo;
    }
}

__global__ void k_scatter(const int* __restrict__ ei, int* __restrict__ cursor,
                          int* __restrict__ csr_src) {
    int t = blockIdx.x * blockDim.x + threadIdx.x;
    if (t >= NT) return;
    int d = edst(ei, t), s = esrc(ei, t);
    int pos = atomicAdd(&cursor[d], 1);
    csr_src[pos] = s;
}

// fused layer-1 softmax + aggregate + bias + elu -> o1 in bf16. 1 wave per node.
__global__ void k_l1(const int* __restrict__ rowstart, const int* __restrict__ csr_src,
                     const float* __restrict__ al_s, const float* __restrict__ al_d,
                     const unsigned short* __restrict__ h1bf, const float* __restrict__ b1,
                     unsigned short* __restrict__ o1bf) {
    int n = blockIdx.x * 4 + (threadIdx.x >> 6);
    int j = threadIdx.x & 63;  // channel
    int h = j >> 3;            // head
    float ald = al_d[n * 8 + h];
    int start = rowstart[n], end = rowstart[n + 1];
    float m = -1e30f;
    for (int e = start + (j & 7); e < end; e += 8) {
        m = fmaxf(m, lrelu(al_s[csr_src[e] * 8 + h] + ald));
    }
    for (int o = 4; o >= 1; o >>= 1) m = fmaxf(m, __shfl_xor(m, o, 8));
    float denom = 0.f, acc = 0.f;
    int e = start;
    for (; e + 1 < end; e += 2) {
        int s0 = csr_src[e], s1 = csr_src[e + 1];
        float ex0 = __expf(lrelu(al_s[s0 * 8 + h] + ald) - m);
        float ex1 = __expf(lrelu(al_s[s1 * 8 + h] + ald) - m);
        denom += ex0 + ex1;
        float hv0 = __uint_as_float(((unsigned)h1bf[s0 * 64 + j]) << 16);
        float hv1 = __uint_as_float(((unsigned)h1bf[s1 * 64 + j]) << 16);
        acc = fmaf(ex0, hv0, fmaf(ex1, hv1, acc));
    }
    if (e < end) {
        int s0 = csr_src[e];
        float ex0 = __expf(lrelu(al_s[s0 * 8 + h] + ald) - m);
        denom += ex0;
        acc = fmaf(ex0, __uint_as_float(((unsigned)h1bf[s0 * 64 + j]) << 16), acc);
    }
    o1bf[n * 64 + j] = f2bf(elu1(acc / denom + b1[j]));
}

// MFMA GEMM: h2 = o1 @ W2 (16 nodes x 512 cols per block, 4 waves x 8 col-tiles).
// A[m=lane&15][k=quad*8+j] from o1bf; B[k=quad*8+j][n=lane&15] from W2bfT (n-major).
// C/D: col=lane&15, row=quad*4+r. Fused layer-2 logits from f32 accumulators.
__global__ void k5b_mfma(const unsigned short* __restrict__ o1bf,
                         const unsigned short* __restrict__ W2bfT,
                         const float* __restrict__ as2, const float* __restrict__ ad2,
                         unsigned short* __restrict__ h2bf,
                         float* __restrict__ al_s2, float* __restrict__ al_d2) {
    __shared__ float redS[4][16], redD[4][16];
    int n0 = blockIdx.x * 16;
    int w = threadIdx.x >> 6, l = threadIdx.x & 63;
    int mcol = l & 15;   // A row (m) / B,C/D col (n)
    int q = l >> 4;      // quad
    const unsigned short* ap = o1bf + (n0 + mcol) * 64 + q * 8;
    short8 a0 = *(const short8*)ap;
    short8 a1 = *(const short8*)(ap + 32);
    float psum[4] = {0.f, 0.f, 0.f, 0.f};
    float pdum[4] = {0.f, 0.f, 0.f, 0.f};
#pragma unroll
    for (int t = 0; t < 8; ++t) {
        int col0 = w * 128 + t * 16;
        const unsigned short* bp = W2bfT + (col0 + mcol) * 64 + q * 8;
        short8 b0 = *(const short8*)bp;
        short8 b1 = *(const short8*)(bp + 32);
        float4v acc = {0.f, 0.f, 0.f, 0.f};
        acc = __builtin_amdgcn_mfma_f32_16x16x32_bf16(a0, b0, acc, 0, 0, 0);
        acc = __builtin_amdgcn_mfma_f32_16x16x32_bf16(a1, b1, acc, 0, 0, 0);
        float a_s = as2[col0 + mcol], a_d = ad2[col0 + mcol];
#pragma unroll
        for (int r = 0; r < 4; ++r) {
            int row = q * 4 + r;
            h2bf[(n0 + row) * 512 + col0 + mcol] = f2bf(acc[r]);
            psum[r] = fmaf(acc[r], a_s, psum[r]);
            pdum[r] = fmaf(acc[r], a_d, pdum[r]);
        }
    }
    // reduce the 16 lanes of each quad (they share the same 4 rows)
#pragma unroll
    for (int r = 0; r < 4; ++r) {
        for (int o = 8; o >= 1; o >>= 1) {
            psum[r] += __shfl_xor(psum[r], o, 16);
            pdum[r] += __shfl_xor(pdum[r], o, 16);
        }
    }
    if (mcol == 0) {
#pragma unroll
        for (int r = 0; r < 4; ++r) {
            redS[w][q * 4 + r] = psum[r];
            redD[w][q * 4 + r] = pdum[r];
        }
    }
    __syncthreads();
    if (threadIdx.x < 16) {
        int node = threadIdx.x;
        al_s2[n0 + node] = redS[0][node] + redS[1][node] + redS[2][node] + redS[3][node];
        al_d2[n0 + node] = redD[0][node] + redD[1][node] + redD[2][node] + redD[3][node];
    }
}

// fused layer-2 softmax + aggregate + bias + elu + block-level mean-pool reduction.
__global__ void k_l2(const int* __restrict__ rowstart, const int* __restrict__ csr_src,
                     const float* __restrict__ al_s2, const float* __restrict__ al_d2,
                     const unsigned short* __restrict__ h2bf, const float* __restrict__ b2,
                     const int* __restrict__ batch, float* __restrict__ sums) {
    __shared__ float ld[4][512];
    int n0 = blockIdx.x * 4;
    int w = threadIdx.x >> 6, lane = threadIdx.x & 63;
    int n = n0 + w;
    float ald = al_d2[n];
    int start = rowstart[n], end = rowstart[n + 1];
    float m = -1e30f;
    for (int e = start + lane; e < end; e += 64) {
        m = fmaxf(m, lrelu(al_s2[csr_src[e]] + ald));
    }
    for (int o = 32; o >= 1; o >>= 1) m = fmaxf(m, __shfl_xor(m, o, 64));
    float denom = 0.f;
    float acc[8] = {0.f, 0.f, 0.f, 0.f, 0.f, 0.f, 0.f, 0.f};
    int e = start;
    for (; e + 1 < end; e += 2) {
        int s0 = csr_src[e], s1 = csr_src[e + 1];
        float ex0 = __expf(lrelu(al_s2[s0] + ald) - m);
        float ex1 = __expf(lrelu(al_s2[s1] + ald) - m);
        denom += ex0 + ex1;
        uint4 a = *(const uint4*)(h2bf + s0 * 512 + lane * 8);
        uint4 b = *(const uint4*)(h2bf + s1 * 512 + lane * 8);
        acc[0] = fmaf(ex0, bflo(a.x), fmaf(ex1, bflo(b.x), acc[0]));
        acc[1] = fmaf(ex0, bfhi(a.x), fmaf(ex1, bfhi(b.x), acc[1]));
        acc[2] = fmaf(ex0, bflo(a.y), fmaf(ex1, bflo(b.y), acc[2]));
        acc[3] = fmaf(ex0, bfhi(a.y), fmaf(ex1, bfhi(b.y), acc[3]));
        acc[4] = fmaf(ex0, bflo(a.z), fmaf(ex1, bflo(b.z), acc[4]));
        acc[5] = fmaf(ex0, bfhi(a.z), fmaf(ex1, bfhi(b.z), acc[5]));
        acc[6] = fmaf(ex0, bflo(a.w), fmaf(ex1, bflo(b.w), acc[6]));
        acc[7] = fmaf(ex0, bfhi(a.w), fmaf(ex1, bfhi(b.w), acc[7]));
    }
    if (e < end) {
        int s0 = csr_src[e];
        float ex0 = __expf(lrelu(al_s2[s0] + ald) - m);
        denom += ex0;
        uint4 a = *(const uint4*)(h2bf + s0 * 512 + lane * 8);
        acc[0] = fmaf(ex0, bflo(a.x), acc[0]);
        acc[1] = fmaf(ex0, bfhi(a.x), acc[1]);
        acc[2] = fmaf(ex0, bflo(a.y), acc[2]);
        acc[3] = fmaf(ex0, bfhi(a.y), acc[3]);
        acc[4] = fmaf(ex0, bflo(a.z), acc[4]);
        acc[5] = fmaf(ex0, bfhi(a.z), acc[5]);
        acc[6] = fmaf(ex0, bflo(a.w), acc[6]);
        acc[7] = fmaf(ex0, bfhi(a.w), acc[7]);
    }
    float inv = 1.f / denom;
    const float* bp = b2 + lane * 8;
    float4 v0, v1;
    v0.x = elu1(acc[0] * inv + bp[0]);
    v0.y = elu1(acc[1] * inv + bp[1]);
    v0.z = elu1(acc[2] * inv + bp[2]);
    v0.w = elu1(acc[3] * inv + bp[3]);
    v1.x = elu1(acc[4] * inv + bp[4]);
    v1.y = elu1(acc[5] * inv + bp[5]);
    v1.z = elu1(acc[6] * inv + bp[6]);
    v1.w = elu1(acc[7] * inv + bp[7]);
    *(float4*)&ld[w][lane * 8] = v0;
    *(float4*)&ld[w][lane * 8 + 4] = v1;
    __syncthreads();
    int t = threadIdx.x;  // channels t and t+256
    int g_prev = batch[n0];
    float a0 = 0.f, a1 = 0.f;
#pragma unroll
    for (int wi = 0; wi < 4; ++wi) {
        int gi = batch[n0 + wi];
        if (gi != g_prev) {
            atomicAdd(&sums[g_prev * 512 + t], a0);
            atomicAdd(&sums[g_prev * 512 + 256 + t], a1);
            a0 = a1 = 0.f;
            g_prev = gi;
        }
        a0 += ld[wi][t];
        a1 += ld[wi][t + 256];
    }
    atomicAdd(&sums[g_prev * 512 + t], a0);
    atomicAdd(&sums[g_prev * 512 + 256 + t], a1);
}

// final: out[g][j] = (sums[g] @ Wo[:,j]) / cnt[g] + bo[j].
__global__ void k_final(const float* __restrict__ sums, const int* __restrict__ gstart,
                        const float* __restrict__ Wo, const float* __restrict__ bo,
                        float* __restrict__ out) {
    __shared__ float sp[512];
    int g = blockIdx.x >> 3;
    int j = (blockIdx.x & 7) * 64 + threadIdx.x;  // 64 threads
    for (int k = threadIdx.x; k < 512; k += 64) sp[k] = sums[g * 512 + k];
    __syncthreads();
    float c = (float)(gstart[g + 1] - gstart[g]);
    float inv = 1.f / (c > 0.f ? c : 1.f);
    float acc = 0.f;
    for (int k = 0; k < 512; ++k) acc = fmaf(sp[k], Wo[k * 512 + j], acc);
    out[g * 512 + j] = fmaf(acc, inv, bo[j]);
}

extern "C" void kernel_launch(void* const* d_in, const int* in_sizes, int n_in,
                              void* d_out, int out_size, void* d_ws, size_t ws_size,
                              hipStream_t stream) {
    const float* x     = (const float*)d_in[0];
    const int*   ei    = (const int*)d_in[1];    // [2, NE]
    const int*   batch = (const int*)d_in[2];    // [NN] sorted
    const float* W1    = (const float*)d_in[3];
    const float* as1   = (const float*)d_in[4];
    const float* ad1   = (const float*)d_in[5];
    const float* b1    = (const float*)d_in[6];
    const float* W2    = (const float*)d_in[7];
    const float* as2   = (const float*)d_in[8];
    const float* ad2   = (const float*)d_in[9];
    const float* b2    = (const float*)d_in[10];
    const float* Wo    = (const float*)d_in[11];
    const float* bo    = (const float*)d_in[12];
    float* out = (float*)d_out;

    // ---- workspace arena (4-byte units) ----
    float* w = (float*)d_ws;
    unsigned short* h1bf  = (unsigned short*)(w + 0);        // NN*64 ushort = 640,000 units
    float* al_s1 = w + 640000;     // 160,000
    float* al_d1 = w + 800000;     // 160,000
    unsigned short* o1bf  = (unsigned short*)(w + 960000);   // NN*64 ushort = 640,000 units
    unsigned short* W2bfT = (unsigned short*)(w + 1600000);  // 32768 ushort = 16,384 units
    unsigned short* h2bf  = (unsigned short*)(w + 1616384);  // NN*512 ushort = 5,120,000 units (byte 6,465,536: 16B aligned)
    float* al_s2 = w + 6736384;    // 20,000
    float* al_d2 = w + 6756384;    // 20,000
    int*   rowstart = (int*)(w + 6776384);   // 20,001
    int*   cursor   = (int*)(w + 6796388);   // 20,000
    int*   csr_src  = (int*)(w + 6816388);   // 340,000
    int*   gstart   = (int*)(w + 7156388);   // 65
    // ---- zero-initialized region ----
    int*   deg  = (int*)(w + 7156456);       // 20,000
    float* sums = w + 7176456;               // 32,768
    // end: 7,209,224 units ≈ 28.8 MB

    hipMemsetAsync(w + 7156456, 0, (size_t)(20000 + 32768) * 4, stream);

    k_hist_h1<<<HB + CB + NN / 4, 256, 0, stream>>>(ei, deg, W2, W2bfT, x, W1, as1, ad1,
                                                    h1bf, al_s1, al_d1);
    k_scan   <<<1, 1024, 0, stream>>>(deg, batch, rowstart, cursor, gstart);
    k_scatter<<<HB, 256, 0, stream>>>(ei, cursor, csr_src);

    k_l1     <<<NN / 4, 256, 0, stream>>>(rowstart, csr_src, al_s1, al_d1, h1bf, b1, o1bf);
    k5b_mfma <<<NN / 16, 256, 0, stream>>>(o1bf, W2bfT, as2, ad2, h2bf, al_s2, al_d2);
    k_l2     <<<NN / 4, 256, 0, stream>>>(rowstart, csr_src, al_s2, al_d2, h2bf, b2, batch, sums);

    k_final  <<<NG * 8, 64, 0, stream>>>(sums, gstart, Wo, bo, out);
}

// Round 9
// 216.548 us; speedup vs baseline: 3.1684x; 1.1449x over previous
//
#include <hip/hip_runtime.h>
#include <math.h>

#define NN 20000      // nodes
#define NE 320000     // edges (without self loops)
#define NT 340000     // edges + self loops
#define NG 64         // graphs
#define HB 1329       // (NT+255)/256 hist blocks
#define CB 128        // W2->bf16 transpose blocks (32768/256)
#define AB 2          // a2p GEMV blocks

using short8  = __attribute__((ext_vector_type(8))) short;   // 8 x bf16 (4 VGPRs)
using float4v = __attribute__((ext_vector_type(4))) float;   // MFMA accumulator

__device__ __forceinline__ float lrelu(float v) { return v > 0.f ? v : 0.2f * v; }
__device__ __forceinline__ float elu1(float v)  { return v > 0.f ? v : (expf(v) - 1.f); }
__device__ __forceinline__ unsigned short f2bf(float f) {
    unsigned u = __float_as_uint(f);
    u += 0x7FFFu + ((u >> 16) & 1u);   // round to nearest even
    return (unsigned short)(u >> 16);
}
__device__ __forceinline__ float bf2f(unsigned short s) {
    return __uint_as_float(((unsigned)s) << 16);
}

__device__ __forceinline__ int esrc(const int* ei, int e) { return e < NE ? ei[e] : (e - NE); }
__device__ __forceinline__ int edst(const int* ei, int e) { return e < NE ? ei[NE + e] : (e - NE); }

// ---------- fused prep: CSR histogram | W2 transpose->bf16 | a2p GEMV | layer-1 transform ----------
__global__ void k_hist_h1(const int* __restrict__ ei, int* __restrict__ deg,
                          const float* __restrict__ W2, unsigned short* __restrict__ W2bfT,
                          const float* __restrict__ as2, const float* __restrict__ ad2,
                          float* __restrict__ a2ps, float* __restrict__ a2pd,
                          const float* __restrict__ x, const float* __restrict__ W1,
                          const float* __restrict__ as1, const float* __restrict__ ad1,
                          unsigned short* __restrict__ h1bf, float* __restrict__ al_s,
                          float* __restrict__ al_d) {
    if (blockIdx.x < HB) {
        int t = blockIdx.x * 256 + threadIdx.x;
        if (t < NT) atomicAdd(&deg[edst(ei, t)], 1);
        return;
    }
    if (blockIdx.x < HB + CB) {
        int t = (blockIdx.x - HB) * 256 + threadIdx.x;  // t = n*64 + k
        int k = t & 63, n = t >> 6;
        W2bfT[t] = f2bf(W2[k * 512 + n]);
        return;
    }
    if (blockIdx.x < HB + CB + AB) {
        // a2p[k] = sum_j W2[k][j] * a[j]   (64x512 GEMV)
        __shared__ float part[4][64];
        const float* av = (blockIdx.x == HB + CB) ? as2 : ad2;
        float* outp     = (blockIdx.x == HB + CB) ? a2ps : a2pd;
        int t = threadIdx.x;
        int k = t & 63, seg = t >> 6;  // seg 0..3, j-range of 128
        float s = 0.f;
        for (int j = seg * 128; j < seg * 128 + 128; ++j)
            s = fmaf(W2[k * 512 + j], av[j], s);
        part[seg][k] = s;
        __syncthreads();
        if (t < 64) outp[t] = part[0][t] + part[1][t] + part[2][t] + part[3][t];
        return;
    }
    int n = (blockIdx.x - HB - CB - AB) * 4 + (threadIdx.x >> 6);
    int j = threadIdx.x & 63;
    float x0 = x[n * 3 + 0], x1 = x[n * 3 + 1], x2 = x[n * 3 + 2];
    float v = fmaf(x0, W1[j], fmaf(x1, W1[64 + j], x2 * W1[128 + j]));
    h1bf[n * 64 + j] = f2bf(v);
    float ps = v * as1[j];
    float pd = v * ad1[j];
    for (int o = 4; o >= 1; o >>= 1) {
        ps += __shfl_xor(ps, o, 8);
        pd += __shfl_xor(pd, o, 8);
    }
    if ((j & 7) == 0) {
        al_s[n * 8 + (j >> 3)] = ps;
        al_d[n * 8 + (j >> 3)] = pd;
    }
}

// single-block: exclusive scan of deg -> rowstart/cursor; binary-search gstart from sorted batch
__global__ void k_scan(const int* __restrict__ deg, const int* __restrict__ batch,
                       int* __restrict__ rowstart, int* __restrict__ cursor,
                       int* __restrict__ gstart) {
    __shared__ int part[1024];
    int t = threadIdx.x;
    int base = t * 20;
    int local[20];
    int s = 0;
    if (base < NN) {
#pragma unroll
        for (int i = 0; i < 20; ++i) { local[i] = deg[base + i]; s += local[i]; }
    }
    part[t] = s;
    __syncthreads();
    for (int o = 1; o < 1024; o <<= 1) {
        int v = (t >= o) ? part[t - o] : 0;
        __syncthreads();
        part[t] += v;
        __syncthreads();
    }
    if (base < NN) {
        int run = (t == 0) ? 0 : part[t - 1];
#pragma unroll
        for (int i = 0; i < 20; ++i) {
            rowstart[base + i] = run;
            cursor[base + i] = run;
            run += local[i];
        }
    }
    if (t == 1023) rowstart[NN] = part[1023];
    if (t <= NG) {
        int lo = 0, hi = NN;
        while (lo < hi) {
            int mid = (lo + hi) >> 1;
            if (batch[mid] < t) lo = mid + 1; else hi = mid;
        }
        gstart[t] = lo;
    }
}

__global__ void k_scatter(const int* __restrict__ ei, int* __restrict__ cursor,
                          int* __restrict__ csr_src) {
    int t = blockIdx.x * blockDim.x + threadIdx.x;
    if (t >= NT) return;
    int d = edst(ei, t), s = esrc(ei, t);
    int pos = atomicAdd(&cursor[d], 1);
    csr_src[pos] = s;
}

// fused layer-1 softmax + aggregate + bias + elu -> o1bf; layer-2 logits from f32 o1.
__global__ void k_l1(const int* __restrict__ rowstart, const int* __restrict__ csr_src,
                     const float* __restrict__ al_s, const float* __restrict__ al_d,
                     const unsigned short* __restrict__ h1bf, const float* __restrict__ b1,
                     const float* __restrict__ a2ps, const float* __restrict__ a2pd,
                     unsigned short* __restrict__ o1bf, float* __restrict__ al_s2,
                     float* __restrict__ al_d2) {
    int n = blockIdx.x * 4 + (threadIdx.x >> 6);
    int j = threadIdx.x & 63;  // channel
    int h = j >> 3;            // head
    float ald = al_d[n * 8 + h];
    int start = rowstart[n], end = rowstart[n + 1];
    float m = -1e30f;
    for (int e = start + (j & 7); e < end; e += 8) {
        m = fmaxf(m, lrelu(al_s[csr_src[e] * 8 + h] + ald));
    }
    for (int o = 4; o >= 1; o >>= 1) m = fmaxf(m, __shfl_xor(m, o, 8));
    float denom = 0.f, acc = 0.f;
    int e = start;
    for (; e + 1 < end; e += 2) {
        int s0 = csr_src[e], s1 = csr_src[e + 1];
        float ex0 = __expf(lrelu(al_s[s0 * 8 + h] + ald) - m);
        float ex1 = __expf(lrelu(al_s[s1 * 8 + h] + ald) - m);
        denom += ex0 + ex1;
        acc = fmaf(ex0, bf2f(h1bf[s0 * 64 + j]), fmaf(ex1, bf2f(h1bf[s1 * 64 + j]), acc));
    }
    if (e < end) {
        int s0 = csr_src[e];
        float ex0 = __expf(lrelu(al_s[s0 * 8 + h] + ald) - m);
        denom += ex0;
        acc = fmaf(ex0, bf2f(h1bf[s0 * 64 + j]), acc);
    }
    float v = elu1(acc / denom + b1[j]);   // f32 o1 value
    o1bf[n * 64 + j] = f2bf(v);
    // layer-2 logits: al_s2[n] = sum_j v*a2ps[j]  (full-wave reduce)
    float ps = v * a2ps[j];
    float pd = v * a2pd[j];
    for (int o = 32; o >= 1; o >>= 1) {
        ps += __shfl_xor(ps, o, 64);
        pd += __shfl_xor(pd, o, 64);
    }
    if (j == 0) { al_s2[n] = ps; al_d2[n] = pd; }
}

// layer-2 softmax + aggregation in the 64-dim o1 space (linearity of W2).
// aggbf[n][64] = bf16( (sum_e ex_e * o1[src_e]) / denom )
__global__ void k_l2agg(const int* __restrict__ rowstart, const int* __restrict__ csr_src,
                        const float* __restrict__ al_s2, const float* __restrict__ al_d2,
                        const unsigned short* __restrict__ o1bf,
                        unsigned short* __restrict__ aggbf) {
    int n = blockIdx.x * 4 + (threadIdx.x >> 6);
    int j = threadIdx.x & 63;  // channel
    float ald = al_d2[n];
    int start = rowstart[n], end = rowstart[n + 1];
    float m = -1e30f;
    for (int e = start + j; e < end; e += 64) {
        m = fmaxf(m, lrelu(al_s2[csr_src[e]] + ald));
    }
    for (int o = 32; o >= 1; o >>= 1) m = fmaxf(m, __shfl_xor(m, o, 64));
    float denom = 0.f, acc = 0.f;
    int e = start;
    for (; e + 1 < end; e += 2) {
        int s0 = csr_src[e], s1 = csr_src[e + 1];
        float ex0 = __expf(lrelu(al_s2[s0] + ald) - m);
        float ex1 = __expf(lrelu(al_s2[s1] + ald) - m);
        denom += ex0 + ex1;
        acc = fmaf(ex0, bf2f(o1bf[s0 * 64 + j]), fmaf(ex1, bf2f(o1bf[s1 * 64 + j]), acc));
    }
    if (e < end) {
        int s0 = csr_src[e];
        float ex0 = __expf(lrelu(al_s2[s0] + ald) - m);
        denom += ex0;
        acc = fmaf(ex0, bf2f(o1bf[s0 * 64 + j]), acc);
    }
    aggbf[n * 64 + j] = f2bf(acc / denom);
}

// MFMA GEMM: out2 = agg @ W2 + b2, elu, then graph-masked pool into sums. No o2 store.
// 16 nodes x 512 cols per block; 4 waves x 8 col-tiles.
__global__ void k_gemm2(const unsigned short* __restrict__ aggbf,
                        const unsigned short* __restrict__ W2bfT,
                        const float* __restrict__ b2, const int* __restrict__ batch,
                        float* __restrict__ sums) {
    int n0 = blockIdx.x * 16;
    int w = threadIdx.x >> 6, l = threadIdx.x & 63;
    int mcol = l & 15;   // A row (m) / B,C/D col (n)
    int q = l >> 4;      // quad
    const unsigned short* ap = aggbf + (n0 + mcol) * 64 + q * 8;
    short8 a0 = *(const short8*)ap;
    short8 a1 = *(const short8*)(ap + 32);
    int gmin = batch[n0], gmax = batch[n0 + 15];
    int batchq[4];
#pragma unroll
    for (int r = 0; r < 4; ++r) batchq[r] = batch[n0 + q * 4 + r];
#pragma unroll
    for (int t = 0; t < 8; ++t) {
        int col0 = w * 128 + t * 16;
        int c = col0 + mcol;
        const unsigned short* bp = W2bfT + c * 64 + q * 8;
        short8 b0 = *(const short8*)bp;
        short8 b1 = *(const short8*)(bp + 32);
        float4v acc = {0.f, 0.f, 0.f, 0.f};
        acc = __builtin_amdgcn_mfma_f32_16x16x32_bf16(a0, b0, acc, 0, 0, 0);
        acc = __builtin_amdgcn_mfma_f32_16x16x32_bf16(a1, b1, acc, 0, 0, 0);
        float bias = b2[c];
        float val[4];
#pragma unroll
        for (int r = 0; r < 4; ++r) val[r] = elu1(acc[r] + bias);
        // pool over the block's 16 rows, grouped by graph (batch sorted)
        for (int g = gmin; g <= gmax; ++g) {
            float s = 0.f;
#pragma unroll
            for (int r = 0; r < 4; ++r) s += (batchq[r] == g) ? val[r] : 0.f;
            s += __shfl_xor(s, 16, 64);   // reduce across the 4 quads
            s += __shfl_xor(s, 32, 64);
            if (q == 0) atomicAdd(&sums[g * 512 + c], s);
        }
    }
}

// final: out[g][j] = (sums[g] @ Wo[:,j]) / cnt[g] + bo[j].
__global__ void k_final(const float* __restrict__ sums, const int* __restrict__ gstart,
                        const float* __restrict__ Wo, const float* __restrict__ bo,
                        float* __restrict__ out) {
    __shared__ float sp[512];
    int g = blockIdx.x >> 3;
    int j = (blockIdx.x & 7) * 64 + threadIdx.x;  // 64 threads
    for (int k = threadIdx.x; k < 512; k += 64) sp[k] = sums[g * 512 + k];
    __syncthreads();
    float c = (float)(gstart[g + 1] - gstart[g]);
    float inv = 1.f / (c > 0.f ? c : 1.f);
    float acc = 0.f;
    for (int k = 0; k < 512; ++k) acc = fmaf(sp[k], Wo[k * 512 + j], acc);
    out[g * 512 + j] = fmaf(acc, inv, bo[j]);
}

extern "C" void kernel_launch(void* const* d_in, const int* in_sizes, int n_in,
                              void* d_out, int out_size, void* d_ws, size_t ws_size,
                              hipStream_t stream) {
    const float* x     = (const float*)d_in[0];
    const int*   ei    = (const int*)d_in[1];    // [2, NE]
    const int*   batch = (const int*)d_in[2];    // [NN] sorted
    const float* W1    = (const float*)d_in[3];
    const float* as1   = (const float*)d_in[4];
    const float* ad1   = (const float*)d_in[5];
    const float* b1    = (const float*)d_in[6];
    const float* W2    = (const float*)d_in[7];
    const float* as2   = (const float*)d_in[8];
    const float* ad2   = (const float*)d_in[9];
    const float* b2    = (const float*)d_in[10];
    const float* Wo    = (const float*)d_in[11];
    const float* bo    = (const float*)d_in[12];
    float* out = (float*)d_out;

    // ---- workspace arena (4-byte units) ----
    float* w = (float*)d_ws;
    unsigned short* h1bf  = (unsigned short*)(w + 0);        // NN*64 ushort = 640,000 units
    float* al_s1 = w + 640000;     // 160,000
    float* al_d1 = w + 800000;     // 160,000
    unsigned short* o1bf  = (unsigned short*)(w + 960000);   // 640,000 units (byte 3,840,000: 128B aligned)
    unsigned short* W2bfT = (unsigned short*)(w + 1600000);  // 16,384 units
    float* a2ps  = w + 1616384;    // 64
    float* a2pd  = w + 1616448;    // 64
    float* al_s2 = w + 1616512;    // 20,000
    float* al_d2 = w + 1636512;    // 20,000
    unsigned short* aggbf = (unsigned short*)(w + 1656512);  // 640,000 units (byte 6,626,048: 128B aligned)
    int*   rowstart = (int*)(w + 2296512);   // 20,001
    int*   cursor   = (int*)(w + 2316516);   // 20,000
    int*   csr_src  = (int*)(w + 2336516);   // 340,000
    int*   gstart   = (int*)(w + 2676516);   // 65
    // ---- zero-initialized region ----
    int*   deg  = (int*)(w + 2676584);       // 20,000
    float* sums = w + 2696584;               // 32,768
    // end: 2,729,352 units ≈ 10.9 MB

    hipMemsetAsync(w + 2676584, 0, (size_t)(20000 + 32768) * 4, stream);

    k_hist_h1<<<HB + CB + AB + NN / 4, 256, 0, stream>>>(ei, deg, W2, W2bfT, as2, ad2,
                                                         a2ps, a2pd, x, W1, as1, ad1,
                                                         h1bf, al_s1, al_d1);
    k_scan   <<<1, 1024, 0, stream>>>(deg, batch, rowstart, cursor, gstart);
    k_scatter<<<HB, 256, 0, stream>>>(ei, cursor, csr_src);

    k_l1     <<<NN / 4, 256, 0, stream>>>(rowstart, csr_src, al_s1, al_d1, h1bf, b1,
                                          a2ps, a2pd, o1bf, al_s2, al_d2);
    k_l2agg  <<<NN / 4, 256, 0, stream>>>(rowstart, csr_src, al_s2, al_d2, o1bf, aggbf);
    k_gemm2  <<<NN / 16, 256, 0, stream>>>(aggbf, W2bfT, b2, batch, sums);

    k_final  <<<NG * 8, 64, 0, stream>>>(sums, gstart, Wo, bo, out);
}